// Round 6
// baseline (647.359 us; speedup 1.0000x reference)
//
#include <hip/hip_runtime.h>

#define DEV __device__ __forceinline__

typedef short bf16x8 __attribute__((ext_vector_type(8)));
typedef float f32x4 __attribute__((ext_vector_type(4)));
typedef unsigned int uint;

// raw barrier / counted waits (no compiler-attached drains)
#define SBAR()   asm volatile("s_barrier" ::: "memory")
#define WAITV(n) asm volatile("s_waitcnt vmcnt(" #n ")" ::: "memory")
#define WAITL()  asm volatile("s_waitcnt lgkmcnt(0)" ::: "memory")

// ---------- helpers ----------
DEV unsigned short f2b(float f) {               // fp32 -> bf16 RNE
    uint u = __float_as_uint(f);
    u += 0x7fffu + ((u >> 16) & 1u);
    return (unsigned short)(u >> 16);
}
DEV uint packbf2(float a, float b) { return (uint)f2b(a) | ((uint)f2b(b) << 16); }
DEV float b2f(unsigned short s) { return __uint_as_float(((uint)s) << 16); }
DEV float b2f_lo(uint u) { return __uint_as_float(u << 16); }
DEV float b2f_hi(uint u) { return __uint_as_float(u & 0xffff0000u); }

DEV void async_cp16(const void* g, void* l) {   // global -> LDS, 16B/lane
    __builtin_amdgcn_global_load_lds(
        (const __attribute__((address_space(1))) unsigned int*)g,
        (__attribute__((address_space(3))) unsigned int*)l, 16, 0, 0);
}

DEV float quad_sum(float x) {                   // sum over 4-lane quad via DPP
    x += __int_as_float(__builtin_amdgcn_update_dpp(0, __float_as_int(x), 0xB1, 0xF, 0xF, true));
    x += __int_as_float(__builtin_amdgcn_update_dpp(0, __float_as_int(x), 0x4E, 0xF, 0xF, true));
    return x;
}

DEV float gelu_f(float u) {                     // tanh-approx gelu via sigmoid/exp
    float p = u + 0.044715f * u * u * u;
    float e = __expf(-1.5957691216f * p);       // 0.5(1+tanh(cp)) = sigmoid(2cp)
    return __fdividef(u, 1.f + e);
}

// decode 8 bf16 (uint4) -> 8 floats
DEV void dec8(uint4 p, float* o) {
    o[0] = b2f_lo(p.x); o[1] = b2f_hi(p.x); o[2] = b2f_lo(p.y); o[3] = b2f_hi(p.y);
    o[4] = b2f_lo(p.z); o[5] = b2f_hi(p.z); o[6] = b2f_lo(p.w); o[7] = b2f_hi(p.w);
}

// ---------- transpose + cast: in f32 [K][N] -> out bf16 [Npad][K], rows >= N zero ----------
__global__ __launch_bounds__(256) void transpose_cast_k(
    const float* __restrict__ in, unsigned short* __restrict__ out, int K, int N)
{
    __shared__ float tile[32][33];
    const int k0 = blockIdx.x * 32, n0 = blockIdx.y * 32;
    const int tx = threadIdx.x & 31, ty = threadIdx.x >> 5;   // ty 0..7
#pragma unroll
    for (int i = 0; i < 32; i += 8) {
        int n = n0 + tx;
        tile[ty + i][tx] = (n < N) ? in[(size_t)(k0 + ty + i) * N + n] : 0.0f;
    }
    __syncthreads();
#pragma unroll
    for (int i = 0; i < 32; i += 8) {
        out[(size_t)(n0 + ty + i) * K + (k0 + tx)] = f2b(tile[tx][ty + i]);
    }
}

// ---------- concat bias [bq|bk|bv|bbeta|0pad] -> 3328 (padded to 256-col tiles) ----------
__global__ void build_bias_k(const float* __restrict__ bq, const float* __restrict__ bk,
                             const float* __restrict__ bv, const float* __restrict__ bb,
                             float* __restrict__ outb)
{
    int i = blockIdx.x * 256 + threadIdx.x;
    if (i >= 3328) return;
    float v = 0.f;
    if (i < 1024)      v = bq[i];
    else if (i < 2048) v = bk[i - 1024];
    else if (i < 3072) v = bv[i - 2048];
    else if (i < 3088) v = bb[i - 3072];
    outb[i] = v;
}

// ---------- rmsnorm (rows of 1024) + cast to bf16 ----------
__global__ __launch_bounds__(256) void rmsnorm_cast_k(
    const float* __restrict__ x, const float* __restrict__ scale,
    unsigned short* __restrict__ out)
{
    const int row = blockIdx.x;
    const int t = threadIdx.x;
    const float4 v = *(const float4*)(x + (size_t)row * 1024 + t * 4);
    float ss = v.x * v.x + v.y * v.y + v.z * v.z + v.w * v.w;
#pragma unroll
    for (int off = 1; off < 64; off <<= 1) ss += __shfl_xor(ss, off);
    __shared__ float wsum[4];
    if ((t & 63) == 0) wsum[t >> 6] = ss;
    __syncthreads();
    const float tot = wsum[0] + wsum[1] + wsum[2] + wsum[3];
    const float inv = rsqrtf(tot * (1.0f / 1024.0f) + 1e-6f);
    const float4 sc = *(const float4*)(scale + t * 4);
    uint lo = (uint)f2b(v.x * inv * sc.x) | ((uint)f2b(v.y * inv * sc.y) << 16);
    uint hi = (uint)f2b(v.z * inv * sc.z) | ((uint)f2b(v.w * inv * sc.w) << 16);
    uint2 pkd; pkd.x = lo; pkd.y = hi;
    *(uint2*)(out + (size_t)row * 1024 + t * 4) = pkd;
}

// =====================================================================
// gemm256: C[M,N](bf16) = A[M,K] * BT[N,K]^T (+bias, opt gelu)
// 256x256 tile, 512 thr (8 waves = 2M x 4N), per-wave 128x64 out, acc[8][4].
// r6: 2-buffer depth-1 prefetch, 64 KiB LDS -> 2 BLOCKS/CU. The co-resident
// block overlaps this block's LDS/barrier phase with MFMA (fixes the 1-block
// lockstep that capped MfmaUtil at 24%). One barrier per tile. vmcnt(0) is
// waited ~1400cy after issue (12 ds_read + 32 MFMA in between) so HBM
// latency is covered. XOR bank swizzle retained (0 conflicts).
// =====================================================================
template <bool GELU, bool GUARD>
__global__ __launch_bounds__(512, 2) void gemm256(
    const unsigned short* __restrict__ A, const unsigned short* __restrict__ BT,
    const float* __restrict__ bias, unsigned short* __restrict__ C,
    int Nstride, int Nreal, int K)
{
    __shared__ __align__(16) unsigned short As[2][256 * 32];   // 2 x 16 KB
    __shared__ __align__(16) unsigned short Bs[2][256 * 32];   // 2 x 16 KB
    const int tid = threadIdx.x;
    const int wid = tid >> 6;
    const int lane = tid & 63;
    const int l16 = lane & 15, quad = lane >> 4;
    const int wm = wid & 1, wn = wid >> 1;
    const int m0 = blockIdx.x << 8, n0 = blockIdx.y << 8;

    const int srow = (wid << 5) + (lane >> 2);
    const int scol = ((lane & 3) ^ ((lane >> 3) & 3)) << 3;
    const unsigned short* Ag = A + (size_t)(m0 + srow) * K + scol;
    const unsigned short* Bg = BT + (size_t)(n0 + srow) * K + scol;
    const size_t rstep16 = (size_t)16 * K;
    const int ldst = wid << 10;

    f32x4 acc[8][4];
#pragma unroll
    for (int i = 0; i < 8; i++)
#pragma unroll
        for (int j = 0; j < 4; j++) acc[i][j] = (f32x4)0.f;

    const int ksw = (quad ^ ((l16 >> 1) & 3)) << 3;
    const int aoff = ((wm << 7) + l16) * 32 + ksw;
    const int boff = ((wn << 6) + l16) * 32 + ksw;

    const int nt = K >> 5;
    // prologue: stage tile 0 into buf 0
    async_cp16(Ag, &As[0][ldst]);
    async_cp16(Ag + rstep16, &As[0][ldst + 512]);
    async_cp16(Bg, &Bs[0][ldst]);
    async_cp16(Bg + rstep16, &Bs[0][ldst + 512]);
    WAITV(0);
    SBAR();

    for (int tb = 0; tb < nt; tb += 2) {
#pragma unroll
        for (int u = 0; u < 2; ++u) {
            const int t = tb + u;                // t & 1 == u
            const int nb = u ^ 1;
            if (t + 1 < nt) {
                const size_t kp = (size_t)(t + 1) << 5;
                async_cp16(Ag + kp, &As[nb][ldst]);
                async_cp16(Ag + kp + rstep16, &As[nb][ldst + 512]);
                async_cp16(Bg + kp, &Bs[nb][ldst]);
                async_cp16(Bg + kp + rstep16, &Bs[nb][ldst + 512]);
            }
            bf16x8 af[8], bfr[4];
#pragma unroll
            for (int mi = 0; mi < 8; mi++) af[mi] = *(const bf16x8*)&As[u][aoff + mi * 512];
#pragma unroll
            for (int ni = 0; ni < 4; ni++) bfr[ni] = *(const bf16x8*)&Bs[u][boff + ni * 512];
            __builtin_amdgcn_s_setprio(1);
#pragma unroll
            for (int mi = 0; mi < 8; mi++)
#pragma unroll
                for (int ni = 0; ni < 4; ni++)
                    acc[mi][ni] = __builtin_amdgcn_mfma_f32_16x16x32_bf16(af[mi], bfr[ni], acc[mi][ni], 0, 0, 0);
            __builtin_amdgcn_s_setprio(0);
            WAITV(0);                            // next tile landed
            SBAR();
        }
    }

    float bv[4];
    const int ccol = n0 + (wn << 6) + l16;
#pragma unroll
    for (int ni = 0; ni < 4; ni++) bv[ni] = bias[ccol + ni * 16];
#pragma unroll
    for (int mi = 0; mi < 8; mi++) {
        const int row = m0 + (wm << 7) + mi * 16 + (quad << 2);
#pragma unroll
        for (int r = 0; r < 4; r++) {
            unsigned short* Crow = C + (size_t)(row + r) * Nstride + ccol;
#pragma unroll
            for (int ni = 0; ni < 4; ni++) {
                float v = acc[mi][ni][r] + bv[ni];
                if (GELU) v = gelu_f(v);
                if (!GUARD || (ccol + ni * 16) < Nreal) Crow[ni * 16] = f2b(v);
            }
        }
    }
}

// =====================================================================
// gemm128s: C[M,N](f32) = A[M,K] * BT[N,K]^T + bias (+add)
// 128x128 tile, 256 thr (4 waves = 2M x 2N), wave out 64x64, acc[4][4].
// 2-buffer, 32 KiB LDS -> multiple blocks/CU; grid 64x8 = 512 blocks
// (2/CU resident). Same skeleton as gemm256: 1 barrier/tile, vmcnt(0)
// covered by 8 ds_read + 16 MFMA, XOR swizzle. For WO (K=1024) and
// FFN2 (K=4096).
// =====================================================================
template <bool ADD>
__global__ __launch_bounds__(256, 2) void gemm128s(
    const unsigned short* __restrict__ A, const unsigned short* __restrict__ BT,
    const float* __restrict__ bias, const float* __restrict__ add,
    float* __restrict__ C, int N, int K)
{
    __shared__ __align__(16) unsigned short As[2][128 * 32];   // 2 x 8 KB
    __shared__ __align__(16) unsigned short Bs[2][128 * 32];   // 2 x 8 KB
    const int tid = threadIdx.x;
    const int wid = tid >> 6;                 // 0..3
    const int lane = tid & 63;
    const int l16 = lane & 15, quad = lane >> 4;
    const int wm = wid & 1, wn = wid >> 1;    // 2M x 2N
    const int m0 = blockIdx.x << 7, n0 = blockIdx.y << 7;

    // staging: call c covers rows c*64 + tid>>2; physical chunk tid&3,
    // source chunk swizzled by sel(row) = (row>>1)&3 = (tid>>3)&3
    const int srow = tid >> 2;
    const int scol = ((tid & 3) ^ ((tid >> 3) & 3)) << 3;
    const unsigned short* Ag = A + (size_t)(m0 + srow) * K + scol;
    const unsigned short* Bg = BT + (size_t)(n0 + srow) * K + scol;
    const size_t rstep64 = (size_t)64 * K;
    const int ldst = wid << 9;                // wave base within a call (1024 B)

    f32x4 acc[4][4];
#pragma unroll
    for (int i = 0; i < 4; i++)
#pragma unroll
        for (int j = 0; j < 4; j++) acc[i][j] = (f32x4)0.f;

    const int ksw = (quad ^ ((l16 >> 1) & 3)) << 3;
    const int aoff = ((wm << 6) + l16) * 32 + ksw;
    const int boff = ((wn << 6) + l16) * 32 + ksw;

    const int nt = K >> 5;
    // prologue: stage tile 0 into buf 0 (A: 2 calls of 64 rows; B: same)
    async_cp16(Ag, &As[0][ldst]);
    async_cp16(Ag + rstep64, &As[0][2048 + ldst]);
    async_cp16(Bg, &Bs[0][ldst]);
    async_cp16(Bg + rstep64, &Bs[0][2048 + ldst]);
    WAITV(0);
    SBAR();

    for (int tb = 0; tb < nt; tb += 2) {
#pragma unroll
        for (int u = 0; u < 2; ++u) {
            const int t = tb + u;
            const int nb = u ^ 1;
            if (t + 1 < nt) {
                const size_t kp = (size_t)(t + 1) << 5;
                async_cp16(Ag + kp, &As[nb][ldst]);
                async_cp16(Ag + kp + rstep64, &As[nb][2048 + ldst]);
                async_cp16(Bg + kp, &Bs[nb][ldst]);
                async_cp16(Bg + kp + rstep64, &Bs[nb][2048 + ldst]);
            }
            bf16x8 af[4], bfr[4];
#pragma unroll
            for (int mi = 0; mi < 4; mi++) af[mi] = *(const bf16x8*)&As[u][aoff + mi * 512];
#pragma unroll
            for (int ni = 0; ni < 4; ni++) bfr[ni] = *(const bf16x8*)&Bs[u][boff + ni * 512];
            __builtin_amdgcn_s_setprio(1);
#pragma unroll
            for (int mi = 0; mi < 4; mi++)
#pragma unroll
                for (int ni = 0; ni < 4; ni++)
                    acc[mi][ni] = __builtin_amdgcn_mfma_f32_16x16x32_bf16(af[mi], bfr[ni], acc[mi][ni], 0, 0, 0);
            __builtin_amdgcn_s_setprio(0);
            WAITV(0);
            SBAR();
        }
    }

    // epilogue: f32, bias + optional residual add
    const int ccol = n0 + (wn << 6) + l16;
    float bv[4];
#pragma unroll
    for (int ni = 0; ni < 4; ni++) bv[ni] = bias[ccol + ni * 16];
#pragma unroll
    for (int mi = 0; mi < 4; mi++) {
        const int row = m0 + (wm << 6) + mi * 16 + (quad << 2);
#pragma unroll
        for (int r = 0; r < 4; r++) {
#pragma unroll
            for (int ni = 0; ni < 4; ni++) {
                size_t idx = (size_t)(row + r) * N + ccol + ni * 16;
                float v = acc[mi][ni][r] + bv[ni];
                if (ADD) v += add[idx];
                C[idx] = v;
            }
        }
    }
}

// =====================================================================
// Chunked WY delta-rule scan, chunk L=64 (all bf16 tensors, MFMA).
// Tiled global layouts per (bh,ch), flat 4096 ush = 8KB:
//   Wg  : [g_d(8)][t(64)][8]   W[t][d]
//   KTg : [g_t(8)][d(64)][8]   Kn[t][d] transposed
//   ZTg : [g_t(8)][j(64)][8]   Z[t][j] transposed
//   Sg  : [g_d(8)][j(64)][8]   chunk-start S[j][d] tiled (= prop's SbU)
//   YTg : [g_t(8)][j(64)][8]   Y^T tiled (= prop's ZTb after Y update)
// =====================================================================

// ---------- prep: normalize k in place (bf16 qkv), build A, solve W,Z, emit tiled layouts ----------
__global__ __launch_bounds__(256) void gdn_prep(
    unsigned short* __restrict__ qkv, unsigned short* __restrict__ Wg,
    unsigned short* __restrict__ ZTg, unsigned short* __restrict__ KTg)
{
    const int chunk = blockIdx.x, bh = blockIdx.y;
    const int b = bh >> 4, h = bh & 15;
    __shared__ float Ks[64 * 68];
    __shared__ float Ws[64 * 65];
    __shared__ float Zs[64 * 65];
    __shared__ float Asl[64 * 65];
    __shared__ float bs[64];
    const int tid = threadIdx.x;
    const int t = tid >> 2, c = tid & 3;
    unsigned short* rowp = qkv + (size_t)(b * 2048 + chunk * 64 + t) * 3200;

    // phase 1a: load k slice (bf16), row norm, write Kn to LDS + back to global
    float kn[16];
    {
        uint4 ka = *(const uint4*)(rowp + 1024 + h * 64 + 16 * c);
        uint4 kb = *(const uint4*)(rowp + 1024 + h * 64 + 16 * c + 8);
        dec8(ka, kn); dec8(kb, kn + 8);
    }
    float ss = 0.f;
#pragma unroll
    for (int j = 0; j < 16; j++) ss += kn[j] * kn[j];
    ss = quad_sum(ss);
    const float inv = 1.f / (sqrtf(ss) + 1e-6f);
#pragma unroll
    for (int j = 0; j < 16; j++) kn[j] *= inv;
#pragma unroll
    for (int j = 0; j < 16; j++) Ks[t * 68 + 16 * c + j] = kn[j];
    {
        uint4 p0, p1;
        p0.x = packbf2(kn[0], kn[1]);  p0.y = packbf2(kn[2], kn[3]);
        p0.z = packbf2(kn[4], kn[5]);  p0.w = packbf2(kn[6], kn[7]);
        p1.x = packbf2(kn[8], kn[9]);  p1.y = packbf2(kn[10], kn[11]);
        p1.z = packbf2(kn[12], kn[13]); p1.w = packbf2(kn[14], kn[15]);
        *(uint4*)(rowp + 1024 + h * 64 + 16 * c) = p0;
        *(uint4*)(rowp + 1024 + h * 64 + 16 * c + 8) = p1;
    }
    if (c == 0) bs[t] = 1.f / (1.f + __expf(-b2f(rowp[3072 + h])));
    __syncthreads();

    // phase 1b: RHS: W = beta*Kn, Z = beta*V
    const float beta = bs[t];
#pragma unroll
    for (int j = 0; j < 16; j++) Ws[t * 65 + 16 * c + j] = beta * kn[j];
    {
        float vv[16];
        uint4 va = *(const uint4*)(rowp + 2048 + h * 64 + 16 * c);
        uint4 vb = *(const uint4*)(rowp + 2048 + h * 64 + 16 * c + 8);
        dec8(va, vv); dec8(vb, vv + 8);
#pragma unroll
        for (int j = 0; j < 16; j++) Zs[t * 65 + 16 * c + j] = beta * vv[j];
    }
    __syncthreads();

    // phase 2: A = strictly_lower(diag(beta) Kn Kn^T); 4x4 tile per thread
    {
        const int tt = tid >> 4, sx = tid & 15;
        float dm[4][4];
#pragma unroll
        for (int i = 0; i < 4; i++)
#pragma unroll
            for (int j = 0; j < 4; j++) dm[i][j] = 0.f;
        for (int d = 0; d < 64; d++) {
            float kt[4], ksv[4];
#pragma unroll
            for (int i = 0; i < 4; i++) kt[i] = Ks[(4 * tt + i) * 68 + d];
#pragma unroll
            for (int j = 0; j < 4; j++) ksv[j] = Ks[(4 * sx + j) * 68 + d];
#pragma unroll
            for (int i = 0; i < 4; i++)
#pragma unroll
                for (int j = 0; j < 4; j++) dm[i][j] += kt[i] * ksv[j];
        }
#pragma unroll
        for (int i = 0; i < 4; i++)
#pragma unroll
            for (int j = 0; j < 4; j++) {
                int T = 4 * tt + i, S_ = 4 * sx + j;
                Asl[T * 65 + S_] = (S_ < T) ? bs[T] * dm[i][j] : 0.f;
            }
    }
    __syncthreads();

    // phase 3: blocked forward substitution (I+A)X = RHS for W and Z
    {
        const int wid = tid >> 6, lane = tid & 63;  // lane = d
        for (int qi = 0; qi < 4; qi++) {
            if (qi > 0) {
                const int tb = qi * 16 + wid * 4;
                float aw[4], az[4];
#pragma unroll
                for (int i = 0; i < 4; i++) { aw[i] = Ws[(tb + i) * 65 + lane]; az[i] = Zs[(tb + i) * 65 + lane]; }
                for (int s = 0; s < qi * 16; s++) {
                    float wsv = Ws[s * 65 + lane], zsv = Zs[s * 65 + lane];
#pragma unroll
                    for (int i = 0; i < 4; i++) {
                        float a = Asl[(tb + i) * 65 + s];
                        aw[i] -= a * wsv; az[i] -= a * zsv;
                    }
                }
#pragma unroll
                for (int i = 0; i < 4; i++) { Ws[(tb + i) * 65 + lane] = aw[i]; Zs[(tb + i) * 65 + lane] = az[i]; }
            }
            __syncthreads();
            if (wid == 0) {
                for (int T = qi * 16; T < qi * 16 + 16; T++) {
                    float a_ = Ws[T * 65 + lane];
                    for (int s = qi * 16; s < T; s++) a_ -= Asl[T * 65 + s] * Ws[s * 65 + lane];
                    Ws[T * 65 + lane] = a_;
                }
            } else if (wid == 1) {
                for (int T = qi * 16; T < qi * 16 + 16; T++) {
                    float a_ = Zs[T * 65 + lane];
                    for (int s = qi * 16; s < T; s++) a_ -= Asl[T * 65 + s] * Zs[s * 65 + lane];
                    Zs[T * 65 + lane] = a_;
                }
            }
            __syncthreads();
        }
    }

    // phase 4: tiled bf16 outputs
    const size_t cbase = ((size_t)bh * 32 + chunk) * 4096;
    // Wg [g_d][t][8] from Ws[t][d]
    {
#pragma unroll
        for (int half = 0; half < 2; half++) {
            uint4 w4;
            w4.x = packbf2(Ws[t * 65 + 16 * c + half * 8 + 0], Ws[t * 65 + 16 * c + half * 8 + 1]);
            w4.y = packbf2(Ws[t * 65 + 16 * c + half * 8 + 2], Ws[t * 65 + 16 * c + half * 8 + 3]);
            w4.z = packbf2(Ws[t * 65 + 16 * c + half * 8 + 4], Ws[t * 65 + 16 * c + half * 8 + 5]);
            w4.w = packbf2(Ws[t * 65 + 16 * c + half * 8 + 6], Ws[t * 65 + 16 * c + half * 8 + 7]);
            *(uint4*)(Wg + cbase + (size_t)((2 * c + half) * 64 + t) * 8) = w4;
        }
    }
    // ZTg [g_t][j][8] from Zs[t][j]
    {
        const int jj = tid >> 2, tq = tid & 3;
#pragma unroll
        for (int half = 0; half < 2; half++) {
            uint4 z4;
            int i0 = half * 8;
            z4.x = packbf2(Zs[(16 * tq + i0 + 0) * 65 + jj], Zs[(16 * tq + i0 + 1) * 65 + jj]);
            z4.y = packbf2(Zs[(16 * tq + i0 + 2) * 65 + jj], Zs[(16 * tq + i0 + 3) * 65 + jj]);
            z4.z = packbf2(Zs[(16 * tq + i0 + 4) * 65 + jj], Zs[(16 * tq + i0 + 5) * 65 + jj]);
            z4.w = packbf2(Zs[(16 * tq + i0 + 6) * 65 + jj], Zs[(16 * tq + i0 + 7) * 65 + jj]);
            *(uint4*)(ZTg + cbase + (size_t)((2 * tq + half) * 64 + jj) * 8) = z4;
        }
    }
    // KTg [g_t][d][8] from Ks[t][d]
    {
        const int dd = tid >> 2, tq = tid & 3;
#pragma unroll
        for (int half = 0; half < 2; half++) {
            uint4 k4;
            int i0 = half * 8;
            k4.x = packbf2(Ks[(16 * tq + i0 + 0) * 68 + dd], Ks[(16 * tq + i0 + 1) * 68 + dd]);
            k4.y = packbf2(Ks[(16 * tq + i0 + 2) * 68 + dd], Ks[(16 * tq + i0 + 3) * 68 + dd]);
            k4.z = packbf2(Ks[(16 * tq + i0 + 4) * 68 + dd], Ks[(16 * tq + i0 + 5) * 68 + dd]);
            k4.w = packbf2(Ks[(16 * tq + i0 + 6) * 68 + dd], Ks[(16 * tq + i0 + 7) * 68 + dd]);
            *(uint4*)(KTg + cbase + (size_t)((2 * tq + half) * 64 + dd) * 8) = k4;
        }
    }
}

// ---------- prop (MFMA): 64 blocks (bh), 4 waves; wave w owns j-rows 16w..16w+15 ----------
// double-buffered chunk staging -- prefetch ch+1 while computing ch
__global__ __launch_bounds__(256, 1) void gdn_prop_mfma(
    const unsigned short* __restrict__ Wg, const unsigned short* __restrict__ KTg,
    const unsigned short* __restrict__ ZTg, unsigned short* __restrict__ Sg,
    unsigned short* __restrict__ YTg)
{
    const int bh = blockIdx.x;
    __shared__ unsigned short WbU[2][4096];   // [g_d][t][8]
    __shared__ unsigned short KTbU[2][4096];  // [g_t][d][8]
    __shared__ unsigned short ZTbU[2][4096];  // [g_t][j][8]; overwritten by Y in place
    __shared__ unsigned short SbU[4096];      // [g_d][j][8]
    const int tid = threadIdx.x;
    const int wid = tid >> 6;
    const int lane = tid & 63;
    const int l16 = lane & 15, quad = lane >> 4;

    f32x4 Sacc[4];   // (j=16wid+quad*4+r, d=16dt+l16)
#pragma unroll
    for (int dt = 0; dt < 4; dt++) Sacc[dt] = (f32x4)0.f;

    // prologue: stage chunk 0
    {
        const size_t cb0 = ((size_t)bh * 32) * 4096;
#pragma unroll
        for (int p = 0; p < 2; p++) {
            const int n = wid * 2 + p;
            async_cp16(Wg + cb0 + n * 512 + lane * 8, &WbU[0][n * 512]);
            async_cp16(KTg + cb0 + n * 512 + lane * 8, &KTbU[0][n * 512]);
            async_cp16(ZTg + cb0 + n * 512 + lane * 8, &ZTbU[0][n * 512]);
        }
    }
    WAITV(0);
    SBAR();

    for (int ch = 0; ch < 32; ch++) {
        const int cur = ch & 1, nxt = cur ^ 1;
        const size_t cbase = ((size_t)bh * 32 + ch) * 4096;
        unsigned short* Wb  = WbU[cur];
        unsigned short* KTb = KTbU[cur];
        unsigned short* ZTb = ZTbU[cur];

        // prefetch next chunk (async; drains under this chunk's compute)
        if (ch + 1 < 32) {
            const size_t cbn = cbase + 4096;
#pragma unroll
            for (int p = 0; p < 2; p++) {
                const int n = wid * 2 + p;
                async_cp16(Wg + cbn + n * 512 + lane * 8, &WbU[nxt][n * 512]);
                async_cp16(KTg + cbn + n * 512 + lane * 8, &KTbU[nxt][n * 512]);
                async_cp16(ZTg + cbn + n * 512 + lane * 8, &ZTbU[nxt][n * 512]);
            }
        }
        // write chunk-start S into SbU (tiled)
#pragma unroll
        for (int dt = 0; dt < 4; dt++) {
#pragma unroll
            for (int r = 0; r < 4; r++) {
                const int j = wid * 16 + quad * 4 + r;
                SbU[((2 * dt + (l16 >> 3)) * 64 + j) * 8 + (l16 & 7)] = f2b(Sacc[dt][r]);
            }
        }
        WAITL();     // own LDS writes done before barrier
        SBAR();      // Sb visible to all waves; prefetch still in flight

        // bulk copy SbU (chunk-start S, tiled) -> global Sg
        {
            uint4 sa0 = *(const uint4*)&SbU[tid * 16];
            uint4 sa1 = *(const uint4*)&SbU[tid * 16 + 8];
            *(uint4*)(Sg + cbase + tid * 16) = sa0;
            *(uint4*)(Sg + cbase + tid * 16 + 8) = sa1;
        }

        // MFMA1': T1^T[j][t] = sum_d Sb[j][d] * Wb[t][d]
        f32x4 t1[4];
#pragma unroll
        for (int tt = 0; tt < 4; tt++) t1[tt] = (f32x4)0.f;
#pragma unroll
        for (int kh = 0; kh < 2; kh++) {
            const int g = kh * 4 + quad;
            bf16x8 afr = *(const bf16x8*)&SbU[(g * 64 + wid * 16 + l16) * 8];
#pragma unroll
            for (int tt = 0; tt < 4; tt++) {
                bf16x8 bfr = *(const bf16x8*)&Wb[(g * 64 + tt * 16 + l16) * 8];
                t1[tt] = __builtin_amdgcn_mfma_f32_16x16x32_bf16(afr, bfr, t1[tt], 0, 0, 0);
            }
        }
        // Y = Z - T1: in-place into ZTb (as YT[j][t]); own wave's j-rows only
#pragma unroll
        for (int tt = 0; tt < 4; tt++) {
            const int t = tt * 16 + l16;
            const int gb = (t >> 3) * 64;
            unsigned short ybf[4];
#pragma unroll
            for (int r = 0; r < 4; r++) {
                const int j = wid * 16 + quad * 4 + r;
                const float z = b2f(ZTb[(gb + j) * 8 + (t & 7)]);
                ybf[r] = f2b(z - t1[tt][r]);
            }
#pragma unroll
            for (int r = 0; r < 4; r++) {
                const int j = wid * 16 + quad * 4 + r;
                ZTb[(gb + j) * 8 + (t & 7)] = ybf[r];
            }
        }
        // MFMA2: S[j][d] += sum_t YT[j][t] * KT[d][t]
#pragma unroll
        for (int kh = 0; kh < 2; kh++) {
            const int g = kh * 4 + quad;
            bf16x8 afr = *(const bf16x8*)&ZTb[(g * 64 + wid * 16 + l16) * 8];
#pragma unroll
            for (int dt = 0; dt < 4; dt++) {
                bf16x8 bfr = *(const bf16x8*)&KTb[(g * 64 + dt * 16 + l16) * 8];
                Sacc[dt] = __builtin_amdgcn_mfma_f32_16x16x32_bf16(afr, bfr, Sacc[dt], 0, 0, 0);
            }
        }
        // bulk copy own wave's YT rows (tiled) -> global YTg
#pragma unroll
        for (int pp = 0; pp < 2; pp++) {
            const int p = lane * 2 + pp;            // 0..127
            const int g = p >> 4, jj = p & 15;
            const int off = (g * 64 + wid * 16 + jj) * 8;
            uint4 yv = *(const uint4*)&ZTb[off];
            *(uint4*)(YTg + cbase + off) = yv;
        }
        WAITV(0);    // next chunk's tiles landed
        SBAR();
    }
}

// ---------- output (MFMA): per (bh, chunk): O = Q S_c^T + tril(Q Kn^T) Y ----------
__global__ __launch_bounds__(256) void gdn_out(
    const unsigned short* __restrict__ qkv, const unsigned short* __restrict__ YTg,
    const unsigned short* __restrict__ Sg, unsigned short* __restrict__ attn)
{
    const int chunk = blockIdx.x, bh = blockIdx.y;
    const int b = bh >> 4, h = bh & 15;
    __shared__ unsigned short QbU[8 * 516];   // [g_d][t][8]  Q
    __shared__ unsigned short KbU[8 * 516];   // [g_d][s][8]  Kn
    __shared__ unsigned short StU[8 * 516];   // [g_d][j][8]  S
    __shared__ unsigned short YtU[8 * 516];   // [g_s][j][8]  Y^T
    __shared__ unsigned short MhU[8 * 516];   // [g_s][t][8]  M hi
    __shared__ unsigned short MlU[8 * 516];   // [g_s][t][8]  M lo
    const int tid = threadIdx.x;
    const int wid = tid >> 6, lane = tid & 63;
    const int l16 = lane & 15, quad = lane >> 4;
    const size_t cbase = ((size_t)bh * 32 + chunk) * 4096;

    // ---- stage: Q,K from qkv rows; St,Yt from packed tiled global ----
    {
        const int t = tid >> 2, c = tid & 3;
        const unsigned short* rowp = qkv + (size_t)(b * 2048 + chunk * 64 + t) * 3200;
        uint4 qa = *(const uint4*)(rowp + h * 64 + 16 * c);
        uint4 qb = *(const uint4*)(rowp + h * 64 + 16 * c + 8);
        uint4 ka = *(const uint4*)(rowp + 1024 + h * 64 + 16 * c);
        uint4 kb = *(const uint4*)(rowp + 1024 + h * 64 + 16 * c + 8);
        *(uint4*)&QbU[(2 * c) * 516 + t * 8]     = qa;
        *(uint4*)&QbU[(2 * c + 1) * 516 + t * 8] = qb;
        *(uint4*)&KbU[(2 * c) * 516 + t * 8]     = ka;
        *(uint4*)&KbU[(2 * c + 1) * 516 + t * 8] = kb;
        const int g = tid >> 5, row = (tid * 2) & 63;
        uint4 s0 = *(const uint4*)(Sg + cbase + tid * 16);
        uint4 s1 = *(const uint4*)(Sg + cbase + tid * 16 + 8);
        *(uint4*)&StU[g * 516 + row * 8]       = s0;
        *(uint4*)&StU[g * 516 + (row + 1) * 8] = s1;
        uint4 y0 = *(const uint4*)(YTg + cbase + tid * 16);
        uint4 y1 = *(const uint4*)(YTg + cbase + tid * 16 + 8);
        *(uint4*)&YtU[g * 516 + row * 8]       = y0;
        *(uint4*)&YtU[g * 516 + (row + 1) * 8] = y1;
    }
    __syncthreads();

    f32x4 m[4], o[4];
#pragma unroll
    for (int i = 0; i < 4; i++) { m[i] = (f32x4)0.f; o[i] = (f32x4)0.f; }

    // M = Q Kn^T  and  O1 = Q S^T   (A = Q rows of own t-block)
#pragma unroll
    for (int kh = 0; kh < 2; kh++) {
        const int g = kh * 4 + quad;
        bf16x8 afr = *(const bf16x8*)&QbU[g * 516 + (wid * 16 + l16) * 8];
#pragma unroll
        for (int st = 0; st < 4; st++) {
            bf16x8 bk = *(const bf16x8*)&KbU[g * 516 + (st * 16 + l16) * 8];
            m[st] = __builtin_amdgcn_mfma_f32_16x16x32_bf16(afr, bk, m[st], 0, 0, 0);
        }
#pragma unroll
        for (int jt = 0; jt < 4; jt++) {
            bf16x8 bs_ = *(const bf16x8*)&StU[g * 516 + (jt * 16 + l16) * 8];
            o[jt] = __builtin_amdgcn_mfma_f32_16x16x32_bf16(afr, bs_, o[jt], 0, 0, 0);
        }
    }

    // tril mask + bf16 hi/lo split -> MbU tiled [g_s][t][8]
#pragma unroll
    for (int st = 0; st < 4; st++) {
#pragma unroll
        for (int r = 0; r < 4; r++) {
            const int t = wid * 16 + quad * 4 + r;
            const int s = st * 16 + l16;
            float v = (s <= t) ? m[st][r] : 0.f;
            unsigned short hi = f2b(v);
            unsigned short lo = f2b(v - b2f(hi));
            const int addr = (s >> 3) * 516 + t * 8 + (s & 7);
            MhU[addr] = hi;
            MlU[addr] = lo;
        }
    }
    __syncthreads();

    // O += (Mhi + Mlo) * Y
#pragma unroll
    for (int kh = 0; kh < 2; kh++) {
        const int g = kh * 4 + quad;
        bf16x8 ah = *(const bf16x8*)&MhU[g * 516 + (wid * 16 + l16) * 8];
        bf16x8 al = *(const bf16x8*)&MlU[g * 516 + (wid * 16 + l16) * 8];
#pragma unroll
        for (int jt = 0; jt < 4; jt++) {
            bf16x8 by = *(const bf16x8*)&YtU[g * 516 + (jt * 16 + l16) * 8];
            o[jt] = __builtin_amdgcn_mfma_f32_16x16x32_bf16(ah, by, o[jt], 0, 0, 0);
            o[jt] = __builtin_amdgcn_mfma_f32_16x16x32_bf16(al, by, o[jt], 0, 0, 0);
        }
    }

    // epilogue: attn[t][h*64 + j] bf16
#pragma unroll
    for (int jt = 0; jt < 4; jt++) {
#pragma unroll
        for (int r = 0; r < 4; r++) {
            const int t = wid * 16 + quad * 4 + r;
            attn[(size_t)(b * 2048 + chunk * 64 + t) * 1024 + h * 64 + jt * 16 + l16] = f2b(o[jt][r]);
        }
    }
}

// ---------- workspace layout (bytes) ----------
static constexpr size_t OFF_H     = 0;                          // 16,777,216  hbuf bf16 / Sg bf16
static constexpr size_t OFF_WQKVT = OFF_H + 16777216;           //  6,553,600  (unused this rev)
static constexpr size_t OFF_WOT   = OFF_WQKVT + 6553600;        //  2,097,152
static constexpr size_t OFF_W1T   = OFF_WOT + 2097152;          //  8,388,608
static constexpr size_t OFF_W2T   = OFF_W1T + 8388608;          //  8,388,608
static constexpr size_t OFF_BIAS  = OFF_W2T + 8388608;          //     16,384
static constexpr size_t OFF_QKV   = OFF_BIAS + 16384;           // 67,108,864  qkv bf16 / gbuf bf16
static constexpr size_t OFF_ATTN  = OFF_QKV + 67108864;         // 16,777,216  bf16
static constexpr size_t OFF_Y1    = OFF_ATTN + 16777216;        // 33,554,432  y1 f32 / (ZTg+KTg bf16)
static constexpr size_t OFF_WG    = OFF_Y1 + 33554432;          // 16,777,216  Wg bf16 / wqkvT(3328x1024) early
static constexpr size_t OFF_YG    = OFF_WG + 16777216;          // 16,777,216  YTg bf16

extern "C" void kernel_launch(void* const* d_in, const int* in_sizes, int n_in,
                              void* d_out, int out_size, void* d_ws, size_t ws_size,
                              hipStream_t stream)
{
    const float* x     = (const float*)d_in[0];
    const float* wq    = (const float*)d_in[1];
    const float* bq    = (const float*)d_in[2];
    const float* wk    = (const float*)d_in[3];
    const float* bk    = (const float*)d_in[4];
    const float* wv    = (const float*)d_in[5];
    const float* bv    = (const float*)d_in[6];
    const float* wbeta = (const float*)d_in[7];
    const float* bbeta = (const float*)d_in[8];
    const float* wo    = (const float*)d_in[9];
    const float* bo    = (const float*)d_in[10];
    const float* w1    = (const float*)d_in[11];
    const float* b1    = (const float*)d_in[12];
    const float* w2    = (const float*)d_in[13];
    const float* b2    = (const float*)d_in[14];
    const float* ln1   = (const float*)d_in[15];
    const float* ln2   = (const float*)d_in[16];

    char* ws = (char*)d_ws;
    unsigned short* hbuf  = (unsigned short*)(ws + OFF_H);
    unsigned short* Sg    = (unsigned short*)(ws + OFF_H);
    unsigned short* wqkvT = (unsigned short*)(ws + OFF_WG);
    unsigned short* woT   = (unsigned short*)(ws + OFF_WOT);
    unsigned short* w1T   = (unsigned short*)(ws + OFF_W1T);
    unsigned short* w2T   = (unsigned short*)(ws + OFF_W2T);
    float*          biasc = (float*)(ws + OFF_BIAS);
    unsigned short* qkvU  = (unsigned short*)(ws + OFF_QKV);
    unsigned short* gbuf  = (unsigned short*)(ws + OFF_QKV);
    unsigned short* attn  = (unsigned short*)(ws + OFF_ATTN);
    float*          y1    = (float*)(ws + OFF_Y1);
    unsigned short* ZTg   = (unsigned short*)(ws + OFF_Y1);
    unsigned short* KTg   = (unsigned short*)(ws + OFF_Y1 + 16777216);
    unsigned short* Wg    = (unsigned short*)(ws + OFF_WG);
    unsigned short* YTg   = (unsigned short*)(ws + OFF_YG);
    float*          out   = (float*)d_out;

    // weight transpose+cast (B^T bf16 operands); wbeta block padded 3072..3327
    transpose_cast_k<<<dim3(32, 32), 256, 0, stream>>>(wq, wqkvT,               1024, 1024);
    transpose_cast_k<<<dim3(32, 32), 256, 0, stream>>>(wk, wqkvT + 1024 * 1024, 1024, 1024);
    transpose_cast_k<<<dim3(32, 32), 256, 0, stream>>>(wv, wqkvT + 2048 * 1024, 1024, 1024);
    transpose_cast_k<<<dim3(32, 8),  256, 0, stream>>>(wbeta, wqkvT + 3072 * 1024, 1024, 16);
    transpose_cast_k<<<dim3(32, 32), 256, 0, stream>>>(wo, woT, 1024, 1024);
    transpose_cast_k<<<dim3(32, 128), 256, 0, stream>>>(w1, w1T, 1024, 4096);
    transpose_cast_k<<<dim3(128, 32), 256, 0, stream>>>(w2, w2T, 4096, 1024);
    build_bias_k<<<13, 256, 0, stream>>>(bq, bk, bv, bbeta, biasc);

    // layer
    rmsnorm_cast_k<<<8192, 256, 0, stream>>>(x, ln1, hbuf);
    // QKV: N padded to 3328 (13 col-tiles), stores guarded at 3200;
    // 416 blocks at 2/CU -> all resident, no dispatch tail
    gemm256<false, true><<<dim3(32, 13), 512, 0, stream>>>(hbuf, wqkvT, biasc, qkvU, 3200, 3200, 1024);
    gdn_prep<<<dim3(32, 64), 256, 0, stream>>>(qkvU, Wg, ZTg, KTg);
    gdn_prop_mfma<<<64, 256, 0, stream>>>(Wg, KTg, ZTg, Sg, YTg);
    gdn_out<<<dim3(32, 64), 256, 0, stream>>>(qkvU, YTg, Sg, attn);
    // WO: 128x128 tiles -> grid 64x8 = 512 blocks (2/CU resident)
    gemm128s<true><<<dim3(64, 8), 256, 0, stream>>>(attn, woT, bo, x, y1, 1024, 1024);
    rmsnorm_cast_k<<<8192, 256, 0, stream>>>(y1, ln2, hbuf);
    // FFN1: gelu + bf16
    gemm256<true, false><<<dim3(32, 16), 512, 0, stream>>>(hbuf, w1T, b1, gbuf, 4096, 4096, 1024);
    // FFN2: K=4096, 128x128 tiles -> 512 blocks
    gemm128s<true><<<dim3(64, 8), 256, 0, stream>>>(gbuf, w2T, b2, y1, out, 1024, 4096);
}

// Round 7
// 576.224 us; speedup vs baseline: 1.1235x; 1.1235x over previous
//
#include <hip/hip_runtime.h>

#define DEV __device__ __forceinline__

typedef short bf16x8 __attribute__((ext_vector_type(8)));
typedef float f32x4 __attribute__((ext_vector_type(4)));
typedef unsigned int uint;

// raw barrier / counted waits (no compiler-attached drains)
#define SBAR()   asm volatile("s_barrier" ::: "memory")
#define WAITV(n) asm volatile("s_waitcnt vmcnt(" #n ")" ::: "memory")
#define WAITL()  asm volatile("s_waitcnt lgkmcnt(0)" ::: "memory")

// ---------- helpers ----------
DEV unsigned short f2b(float f) {               // fp32 -> bf16 RNE
    uint u = __float_as_uint(f);
    u += 0x7fffu + ((u >> 16) & 1u);
    return (unsigned short)(u >> 16);
}
DEV uint packbf2(float a, float b) { return (uint)f2b(a) | ((uint)f2b(b) << 16); }
DEV float b2f(unsigned short s) { return __uint_as_float(((uint)s) << 16); }
DEV float b2f_lo(uint u) { return __uint_as_float(u << 16); }
DEV float b2f_hi(uint u) { return __uint_as_float(u & 0xffff0000u); }

DEV void async_cp16(const void* g, void* l) {   // global -> LDS, 16B/lane
    __builtin_amdgcn_global_load_lds(
        (const __attribute__((address_space(1))) unsigned int*)g,
        (__attribute__((address_space(3))) unsigned int*)l, 16, 0, 0);
}

DEV float quad_sum(float x) {                   // sum over 4-lane quad via DPP
    x += __int_as_float(__builtin_amdgcn_update_dpp(0, __float_as_int(x), 0xB1, 0xF, 0xF, true));
    x += __int_as_float(__builtin_amdgcn_update_dpp(0, __float_as_int(x), 0x4E, 0xF, 0xF, true));
    return x;
}

DEV float gelu_f(float u) {                     // tanh-approx gelu via sigmoid/exp
    float p = u + 0.044715f * u * u * u;
    float e = __expf(-1.5957691216f * p);       // 0.5(1+tanh(cp)) = sigmoid(2cp)
    return __fdividef(u, 1.f + e);
}

// decode 8 bf16 (uint4) -> 8 floats
DEV void dec8(uint4 p, float* o) {
    o[0] = b2f_lo(p.x); o[1] = b2f_hi(p.x); o[2] = b2f_lo(p.y); o[3] = b2f_hi(p.y);
    o[4] = b2f_lo(p.z); o[5] = b2f_hi(p.z); o[6] = b2f_lo(p.w); o[7] = b2f_hi(p.w);
}

// ---------- batched weight prep: all 7 transposes + bias concat in ONE launch ----------
// segments (32x32 f32->bf16 transpose tiles): wq/wk/wv (1024 ea), wbeta(256),
// wo(1024), w1(4096), w2(4096) = 12544 tiles; blocks 12544.. handle bias concat.
__global__ __launch_bounds__(256) void weight_prep_k(
    const float* __restrict__ wq, const float* __restrict__ wk,
    const float* __restrict__ wv, const float* __restrict__ wbeta,
    const float* __restrict__ wo, const float* __restrict__ w1,
    const float* __restrict__ w2,
    unsigned short* __restrict__ wqkvT, unsigned short* __restrict__ woT,
    unsigned short* __restrict__ w1T, unsigned short* __restrict__ w2T,
    const float* __restrict__ bq, const float* __restrict__ bk,
    const float* __restrict__ bv, const float* __restrict__ bb,
    float* __restrict__ biasc)
{
    const int id = blockIdx.x;
    if (id >= 12544) {   // bias concat [bq|bk|bv|bbeta|0pad] -> 3328
        int i = (id - 12544) * 256 + threadIdx.x;
        if (i >= 3328) return;
        float v = 0.f;
        if (i < 1024)      v = bq[i];
        else if (i < 2048) v = bk[i - 1024];
        else if (i < 3072) v = bv[i - 2048];
        else if (i < 3088) v = bb[i - 3072];
        biasc[i] = v;
        return;
    }
    const float* in; unsigned short* out; int K, N, KT, loc;
    if (id < 1024)      { in = wq;    out = wqkvT;               K = 1024; N = 1024; KT = 32;  loc = id; }
    else if (id < 2048) { in = wk;    out = wqkvT + 1024 * 1024; K = 1024; N = 1024; KT = 32;  loc = id - 1024; }
    else if (id < 3072) { in = wv;    out = wqkvT + 2048 * 1024; K = 1024; N = 1024; KT = 32;  loc = id - 2048; }
    else if (id < 3328) { in = wbeta; out = wqkvT + 3072 * 1024; K = 1024; N = 16;   KT = 32;  loc = id - 3072; }
    else if (id < 4352) { in = wo;    out = woT;                 K = 1024; N = 1024; KT = 32;  loc = id - 3328; }
    else if (id < 8448) { in = w1;    out = w1T;                 K = 1024; N = 4096; KT = 32;  loc = id - 4352; }
    else                { in = w2;    out = w2T;                 K = 4096; N = 1024; KT = 128; loc = id - 8448; }
    const int k0 = (loc % KT) * 32, n0 = (loc / KT) * 32;

    __shared__ float tile[32][33];
    const int tx = threadIdx.x & 31, ty = threadIdx.x >> 5;   // ty 0..7
#pragma unroll
    for (int i = 0; i < 32; i += 8) {
        int n = n0 + tx;
        tile[ty + i][tx] = (n < N) ? in[(size_t)(k0 + ty + i) * N + n] : 0.0f;
    }
    __syncthreads();
#pragma unroll
    for (int i = 0; i < 32; i += 8) {
        out[(size_t)(n0 + ty + i) * K + (k0 + tx)] = f2b(tile[tx][ty + i]);
    }
}

// ---------- rmsnorm (rows of 1024) + cast to bf16 ----------
__global__ __launch_bounds__(256) void rmsnorm_cast_k(
    const float* __restrict__ x, const float* __restrict__ scale,
    unsigned short* __restrict__ out)
{
    const int row = blockIdx.x;
    const int t = threadIdx.x;
    const float4 v = *(const float4*)(x + (size_t)row * 1024 + t * 4);
    float ss = v.x * v.x + v.y * v.y + v.z * v.z + v.w * v.w;
#pragma unroll
    for (int off = 1; off < 64; off <<= 1) ss += __shfl_xor(ss, off);
    __shared__ float wsum[4];
    if ((t & 63) == 0) wsum[t >> 6] = ss;
    __syncthreads();
    const float tot = wsum[0] + wsum[1] + wsum[2] + wsum[3];
    const float inv = rsqrtf(tot * (1.0f / 1024.0f) + 1e-6f);
    const float4 sc = *(const float4*)(scale + t * 4);
    uint lo = (uint)f2b(v.x * inv * sc.x) | ((uint)f2b(v.y * inv * sc.y) << 16);
    uint hi = (uint)f2b(v.z * inv * sc.z) | ((uint)f2b(v.w * inv * sc.w) << 16);
    uint2 pkd; pkd.x = lo; pkd.y = hi;
    *(uint2*)(out + (size_t)row * 1024 + t * 4) = pkd;
}

// =====================================================================
// gemm256 (r5-proven, 596us state): C[M,N](bf16) = A[M,K] * BT[N,K]^T
// 256x256 tile, 512 thr (8 waves = 2M x 4N), per-wave 128x64 out, acc[8][4].
// 4-buffer BK=32 pipeline, counted vmcnt, setprio, XOR bank swizzle,
// single 32-MFMA cluster per tile, no explicit lgkmcnt(0) (compiler emits
// counted lgkm per-MFMA so the 12-b128 drain overlaps the cluster).
// =====================================================================
template <bool GELU, bool GUARD>
__global__ __launch_bounds__(512, 2) void gemm256(
    const unsigned short* __restrict__ A, const unsigned short* __restrict__ BT,
    const float* __restrict__ bias, unsigned short* __restrict__ C,
    int Nstride, int Nreal, int K)
{
    __shared__ __align__(16) unsigned short As[4][256 * 32];   // 4 x 16 KB
    __shared__ __align__(16) unsigned short Bs[4][256 * 32];   // 4 x 16 KB
    const int tid = threadIdx.x;
    const int wid = tid >> 6;
    const int lane = tid & 63;
    const int l16 = lane & 15, quad = lane >> 4;
    const int wm = wid & 1, wn = wid >> 1;
    const int m0 = blockIdx.x << 8, n0 = blockIdx.y << 8;

    const int srow = (wid << 5) + (lane >> 2);
    const int scol = ((lane & 3) ^ ((lane >> 3) & 3)) << 3;
    const unsigned short* Ag = A + (size_t)(m0 + srow) * K + scol;
    const unsigned short* Bg = BT + (size_t)(n0 + srow) * K + scol;
    const size_t rstep16 = (size_t)16 * K;
    const int ldst = wid << 10;

    f32x4 acc[8][4];
#pragma unroll
    for (int i = 0; i < 8; i++)
#pragma unroll
        for (int j = 0; j < 4; j++) acc[i][j] = (f32x4)0.f;

    const int ksw = (quad ^ ((l16 >> 1) & 3)) << 3;
    const int aoff = ((wm << 7) + l16) * 32 + ksw;
    const int boff = ((wn << 6) + l16) * 32 + ksw;

    const int nt = K >> 5;
    async_cp16(Ag, &As[0][ldst]);
    async_cp16(Ag + rstep16, &As[0][ldst + 512]);
    async_cp16(Bg, &Bs[0][ldst]);
    async_cp16(Bg + rstep16, &Bs[0][ldst + 512]);
    async_cp16(Ag + 32, &As[1][ldst]);
    async_cp16(Ag + 32 + rstep16, &As[1][ldst + 512]);
    async_cp16(Bg + 32, &Bs[1][ldst]);
    async_cp16(Bg + 32 + rstep16, &Bs[1][ldst + 512]);
    WAITV(4);
    SBAR();

    for (int tb = 0; tb < nt; tb += 4) {
#pragma unroll
        for (int u = 0; u < 4; ++u) {
            const int t = tb + u;                // t & 3 == u
            const int pb = (u + 2) & 3;
            const bool st = (t + 2) < nt;
            const size_t kpre = (size_t)(t + 2) << 5;
            bf16x8 af[8], bfr[4];
            // issue ALL fragment reads for this tile (drain overlaps MFMA
            // via compiler-counted lgkm; no explicit lgkmcnt(0))
#pragma unroll
            for (int mi = 0; mi < 8; mi++) af[mi] = *(const bf16x8*)&As[u][aoff + mi * 512];
#pragma unroll
            for (int ni = 0; ni < 4; ni++) bfr[ni] = *(const bf16x8*)&Bs[u][boff + ni * 512];
            if (st) {
                async_cp16(Ag + kpre, &As[pb][ldst]);
                async_cp16(Ag + kpre + rstep16, &As[pb][ldst + 512]);
                async_cp16(Bg + kpre, &Bs[pb][ldst]);
                async_cp16(Bg + kpre + rstep16, &Bs[pb][ldst + 512]);
                WAITV(4);                        // tile t+1 landed, t+2 in flight
            } else {
                WAITV(0);                        // tail: tile t+1 landed
            }
            SBAR();
            __builtin_amdgcn_s_setprio(1);
#pragma unroll
            for (int mi = 0; mi < 8; mi++)
#pragma unroll
                for (int ni = 0; ni < 4; ni++)
                    acc[mi][ni] = __builtin_amdgcn_mfma_f32_16x16x32_bf16(af[mi], bfr[ni], acc[mi][ni], 0, 0, 0);
            __builtin_amdgcn_s_setprio(0);
            SBAR();
        }
    }

    float bv[4];
    const int ccol = n0 + (wn << 6) + l16;
#pragma unroll
    for (int ni = 0; ni < 4; ni++) bv[ni] = bias[ccol + ni * 16];
#pragma unroll
    for (int mi = 0; mi < 8; mi++) {
        const int row = m0 + (wm << 7) + mi * 16 + (quad << 2);
#pragma unroll
        for (int r = 0; r < 4; r++) {
            unsigned short* Crow = C + (size_t)(row + r) * Nstride + ccol;
#pragma unroll
            for (int ni = 0; ni < 4; ni++) {
                float v = acc[mi][ni][r] + bv[ni];
                if (GELU) v = gelu_f(v);
                if (!GUARD || (ccol + ni * 16) < Nreal) Crow[ni * 16] = f2b(v);
            }
        }
    }
}

// =====================================================================
// gemm128n256 (r5-proven): C[M,N](f32) = A[M,K] * BT[N,K]^T + bias (+add)
// 128x256 tile, 512 thr (8 waves = 2M x 4N), wave out 64x64, acc[4][4].
// =====================================================================
template <bool ADD>
__global__ __launch_bounds__(512, 2) void gemm128n256(
    const unsigned short* __restrict__ A, const unsigned short* __restrict__ BT,
    const float* __restrict__ bias, const float* __restrict__ add,
    float* __restrict__ C, int N, int K)
{
    __shared__ __align__(16) unsigned short As[4][128 * 32];   // 4 x 8 KB
    __shared__ __align__(16) unsigned short Bs[4][256 * 32];   // 4 x 16 KB
    const int tid = threadIdx.x;
    const int wid = tid >> 6;
    const int lane = tid & 63;
    const int l16 = lane & 15, quad = lane >> 4;
    const int wm = wid & 1, wn = wid >> 1;
    const int m0 = blockIdx.x << 7, n0 = blockIdx.y << 8;

    const int arow = (wid << 4) + (lane >> 2);
    const int brow = (wid << 5) + (lane >> 2);
    const int scol = ((lane & 3) ^ ((lane >> 3) & 3)) << 3;
    const unsigned short* Ag = A + (size_t)(m0 + arow) * K + scol;
    const unsigned short* Bg = BT + (size_t)(n0 + brow) * K + scol;
    const size_t rstep16 = (size_t)16 * K;
    const int lda = wid << 9;
    const int ldb = wid << 10;

    f32x4 acc[4][4];
#pragma unroll
    for (int i = 0; i < 4; i++)
#pragma unroll
        for (int j = 0; j < 4; j++) acc[i][j] = (f32x4)0.f;

    const int ksw = (quad ^ ((l16 >> 1) & 3)) << 3;
    const int aoff = ((wm << 6) + l16) * 32 + ksw;
    const int boff = ((wn << 6) + l16) * 32 + ksw;

    const int nt = K >> 5;
    async_cp16(Ag, &As[0][lda]);
    async_cp16(Bg, &Bs[0][ldb]);
    async_cp16(Bg + rstep16, &Bs[0][ldb + 512]);
    async_cp16(Ag + 32, &As[1][lda]);
    async_cp16(Bg + 32, &Bs[1][ldb]);
    async_cp16(Bg + 32 + rstep16, &Bs[1][ldb + 512]);
    WAITV(3);
    SBAR();

    for (int tb = 0; tb < nt; tb += 4) {
#pragma unroll
        for (int u = 0; u < 4; ++u) {
            const int t = tb + u;
            const int pb = (u + 2) & 3;
            const bool st = (t + 2) < nt;
            const size_t kpre = (size_t)(t + 2) << 5;
            bf16x8 af[4], bfr[4];
#pragma unroll
            for (int mi = 0; mi < 4; mi++) af[mi] = *(const bf16x8*)&As[u][aoff + mi * 512];
#pragma unroll
            for (int ni = 0; ni < 4; ni++) bfr[ni] = *(const bf16x8*)&Bs[u][boff + ni * 512];
            if (st) {
                async_cp16(Ag + kpre, &As[pb][lda]);
                async_cp16(Bg + kpre, &Bs[pb][ldb]);
                async_cp16(Bg + kpre + rstep16, &Bs[pb][ldb + 512]);
                WAITV(3);                        // tile t+1 landed, t+2 in flight
            } else {
                WAITV(0);
            }
            SBAR();
            __builtin_amdgcn_s_setprio(1);
#pragma unroll
            for (int mi = 0; mi < 4; mi++)
#pragma unroll
                for (int ni = 0; ni < 4; ni++)
                    acc[mi][ni] = __builtin_amdgcn_mfma_f32_16x16x32_bf16(af[mi], bfr[ni], acc[mi][ni], 0, 0, 0);
            __builtin_amdgcn_s_setprio(0);
            SBAR();
        }
    }

    const int ccol = n0 + (wn << 6) + l16;
    float bv[4];
#pragma unroll
    for (int ni = 0; ni < 4; ni++) bv[ni] = bias[ccol + ni * 16];
#pragma unroll
    for (int mi = 0; mi < 4; mi++) {
        const int row = m0 + (wm << 6) + mi * 16 + (quad << 2);
#pragma unroll
        for (int r = 0; r < 4; r++) {
#pragma unroll
            for (int ni = 0; ni < 4; ni++) {
                size_t idx = (size_t)(row + r) * N + ccol + ni * 16;
                float v = acc[mi][ni][r] + bv[ni];
                if (ADD) v += add[idx];
                C[idx] = v;
            }
        }
    }
}

// =====================================================================
// Chunked WY delta-rule scan, chunk L=64 (all bf16 tensors, MFMA).
// Tiled global layouts per (bh,ch), flat 4096 ush = 8KB:
//   Wg  : [g_d(8)][t(64)][8]   W[t][d]
//   KTg : [g_t(8)][d(64)][8]   Kn[t][d] transposed
//   ZTg : [g_t(8)][j(64)][8]   Z[t][j] transposed
//   Sg  : [g_d(8)][j(64)][8]   chunk-start S[j][d] tiled
//   YTg : [g_t(8)][j(64)][8]   Y^T tiled
// =====================================================================

// ---------- prep: normalize k in place (bf16 qkv), build A, solve W,Z, emit tiled layouts ----------
__global__ __launch_bounds__(256) void gdn_prep(
    unsigned short* __restrict__ qkv, unsigned short* __restrict__ Wg,
    unsigned short* __restrict__ ZTg, unsigned short* __restrict__ KTg)
{
    const int chunk = blockIdx.x, bh = blockIdx.y;
    const int b = bh >> 4, h = bh & 15;
    __shared__ float Ks[64 * 68];
    __shared__ float Ws[64 * 65];
    __shared__ float Zs[64 * 65];
    __shared__ float Asl[64 * 65];
    __shared__ float bs[64];
    const int tid = threadIdx.x;
    const int t = tid >> 2, c = tid & 3;
    unsigned short* rowp = qkv + (size_t)(b * 2048 + chunk * 64 + t) * 3200;

    // phase 1a: load k slice (bf16), row norm, write Kn to LDS + back to global
    float kn[16];
    {
        uint4 ka = *(const uint4*)(rowp + 1024 + h * 64 + 16 * c);
        uint4 kb = *(const uint4*)(rowp + 1024 + h * 64 + 16 * c + 8);
        dec8(ka, kn); dec8(kb, kn + 8);
    }
    float ss = 0.f;
#pragma unroll
    for (int j = 0; j < 16; j++) ss += kn[j] * kn[j];
    ss = quad_sum(ss);
    const float inv = 1.f / (sqrtf(ss) + 1e-6f);
#pragma unroll
    for (int j = 0; j < 16; j++) kn[j] *= inv;
#pragma unroll
    for (int j = 0; j < 16; j++) Ks[t * 68 + 16 * c + j] = kn[j];
    {
        uint4 p0, p1;
        p0.x = packbf2(kn[0], kn[1]);  p0.y = packbf2(kn[2], kn[3]);
        p0.z = packbf2(kn[4], kn[5]);  p0.w = packbf2(kn[6], kn[7]);
        p1.x = packbf2(kn[8], kn[9]);  p1.y = packbf2(kn[10], kn[11]);
        p1.z = packbf2(kn[12], kn[13]); p1.w = packbf2(kn[14], kn[15]);
        *(uint4*)(rowp + 1024 + h * 64 + 16 * c) = p0;
        *(uint4*)(rowp + 1024 + h * 64 + 16 * c + 8) = p1;
    }
    if (c == 0) bs[t] = 1.f / (1.f + __expf(-b2f(rowp[3072 + h])));
    __syncthreads();

    // phase 1b: RHS: W = beta*Kn, Z = beta*V
    const float beta = bs[t];
#pragma unroll
    for (int j = 0; j < 16; j++) Ws[t * 65 + 16 * c + j] = beta * kn[j];
    {
        float vv[16];
        uint4 va = *(const uint4*)(rowp + 2048 + h * 64 + 16 * c);
        uint4 vb = *(const uint4*)(rowp + 2048 + h * 64 + 16 * c + 8);
        dec8(va, vv); dec8(vb, vv + 8);
#pragma unroll
        for (int j = 0; j < 16; j++) Zs[t * 65 + 16 * c + j] = beta * vv[j];
    }
    __syncthreads();

    // phase 2: A = strictly_lower(diag(beta) Kn Kn^T); 4x4 tile per thread
    {
        const int tt = tid >> 4, sx = tid & 15;
        float dm[4][4];
#pragma unroll
        for (int i = 0; i < 4; i++)
#pragma unroll
            for (int j = 0; j < 4; j++) dm[i][j] = 0.f;
        for (int d = 0; d < 64; d++) {
            float kt[4], ksv[4];
#pragma unroll
            for (int i = 0; i < 4; i++) kt[i] = Ks[(4 * tt + i) * 68 + d];
#pragma unroll
            for (int j = 0; j < 4; j++) ksv[j] = Ks[(4 * sx + j) * 68 + d];
#pragma unroll
            for (int i = 0; i < 4; i++)
#pragma unroll
                for (int j = 0; j < 4; j++) dm[i][j] += kt[i] * ksv[j];
        }
#pragma unroll
        for (int i = 0; i < 4; i++)
#pragma unroll
            for (int j = 0; j < 4; j++) {
                int T = 4 * tt + i, S_ = 4 * sx + j;
                Asl[T * 65 + S_] = (S_ < T) ? bs[T] * dm[i][j] : 0.f;
            }
    }
    __syncthreads();

    // phase 3: blocked forward substitution (I+A)X = RHS for W and Z
    {
        const int wid = tid >> 6, lane = tid & 63;  // lane = d
        for (int qi = 0; qi < 4; qi++) {
            if (qi > 0) {
                const int tb = qi * 16 + wid * 4;
                float aw[4], az[4];
#pragma unroll
                for (int i = 0; i < 4; i++) { aw[i] = Ws[(tb + i) * 65 + lane]; az[i] = Zs[(tb + i) * 65 + lane]; }
                for (int s = 0; s < qi * 16; s++) {
                    float wsv = Ws[s * 65 + lane], zsv = Zs[s * 65 + lane];
#pragma unroll
                    for (int i = 0; i < 4; i++) {
                        float a = Asl[(tb + i) * 65 + s];
                        aw[i] -= a * wsv; az[i] -= a * zsv;
                    }
                }
#pragma unroll
                for (int i = 0; i < 4; i++) { Ws[(tb + i) * 65 + lane] = aw[i]; Zs[(tb + i) * 65 + lane] = az[i]; }
            }
            __syncthreads();
            if (wid == 0) {
                for (int T = qi * 16; T < qi * 16 + 16; T++) {
                    float a_ = Ws[T * 65 + lane];
                    for (int s = qi * 16; s < T; s++) a_ -= Asl[T * 65 + s] * Ws[s * 65 + lane];
                    Ws[T * 65 + lane] = a_;
                }
            } else if (wid == 1) {
                for (int T = qi * 16; T < qi * 16 + 16; T++) {
                    float a_ = Zs[T * 65 + lane];
                    for (int s = qi * 16; s < T; s++) a_ -= Asl[T * 65 + s] * Zs[s * 65 + lane];
                    Zs[T * 65 + lane] = a_;
                }
            }
            __syncthreads();
        }
    }

    // phase 4: tiled bf16 outputs
    const size_t cbase = ((size_t)bh * 32 + chunk) * 4096;
    // Wg [g_d][t][8] from Ws[t][d]
    {
#pragma unroll
        for (int half = 0; half < 2; half++) {
            uint4 w4;
            w4.x = packbf2(Ws[t * 65 + 16 * c + half * 8 + 0], Ws[t * 65 + 16 * c + half * 8 + 1]);
            w4.y = packbf2(Ws[t * 65 + 16 * c + half * 8 + 2], Ws[t * 65 + 16 * c + half * 8 + 3]);
            w4.z = packbf2(Ws[t * 65 + 16 * c + half * 8 + 4], Ws[t * 65 + 16 * c + half * 8 + 5]);
            w4.w = packbf2(Ws[t * 65 + 16 * c + half * 8 + 6], Ws[t * 65 + 16 * c + half * 8 + 7]);
            *(uint4*)(Wg + cbase + (size_t)((2 * c + half) * 64 + t) * 8) = w4;
        }
    }
    // ZTg [g_t][j][8] from Zs[t][j]
    {
        const int jj = tid >> 2, tq = tid & 3;
#pragma unroll
        for (int half = 0; half < 2; half++) {
            uint4 z4;
            int i0 = half * 8;
            z4.x = packbf2(Zs[(16 * tq + i0 + 0) * 65 + jj], Zs[(16 * tq + i0 + 1) * 65 + jj]);
            z4.y = packbf2(Zs[(16 * tq + i0 + 2) * 65 + jj], Zs[(16 * tq + i0 + 3) * 65 + jj]);
            z4.z = packbf2(Zs[(16 * tq + i0 + 4) * 65 + jj], Zs[(16 * tq + i0 + 5) * 65 + jj]);
            z4.w = packbf2(Zs[(16 * tq + i0 + 6) * 65 + jj], Zs[(16 * tq + i0 + 7) * 65 + jj]);
            *(uint4*)(ZTg + cbase + (size_t)((2 * tq + half) * 64 + jj) * 8) = z4;
        }
    }
    // KTg [g_t][d][8] from Ks[t][d]
    {
        const int dd = tid >> 2, tq = tid & 3;
#pragma unroll
        for (int half = 0; half < 2; half++) {
            uint4 k4;
            int i0 = half * 8;
            k4.x = packbf2(Ks[(16 * tq + i0 + 0) * 68 + dd], Ks[(16 * tq + i0 + 1) * 68 + dd]);
            k4.y = packbf2(Ks[(16 * tq + i0 + 2) * 68 + dd], Ks[(16 * tq + i0 + 3) * 68 + dd]);
            k4.z = packbf2(Ks[(16 * tq + i0 + 4) * 68 + dd], Ks[(16 * tq + i0 + 5) * 68 + dd]);
            k4.w = packbf2(Ks[(16 * tq + i0 + 6) * 68 + dd], Ks[(16 * tq + i0 + 7) * 68 + dd]);
            *(uint4*)(KTg + cbase + (size_t)((2 * tq + half) * 64 + dd) * 8) = k4;
        }
    }
}

// ---------- prop (MFMA, j-split x4): grid (64 bh, 4 js), ONE wave per block ----------
// The WY recurrence is row-independent in j: each block owns 16 j-rows
// (jb = js*16) and carries its Sacc slice across all 32 chunks. No barriers:
// the wave stages everything it reads (own counted vmcnt suffices). W/KT
// fetched by 4 blocks per bh; bh-major grid puts them on the same XCD so
// L2 absorbs the redundancy. Math identical to the 4-wave version.
__global__ __launch_bounds__(64, 1) void gdn_prop_mfma(
    const unsigned short* __restrict__ Wg, const unsigned short* __restrict__ KTg,
    const unsigned short* __restrict__ ZTg, unsigned short* __restrict__ Sg,
    unsigned short* __restrict__ YTg)
{
    const int bh = blockIdx.x;
    const int jb = blockIdx.y << 4;             // own j-rows jb..jb+15
    __shared__ unsigned short Wb[2][4096];      // [g_d(8)][t(64)][8]
    __shared__ unsigned short KTb[2][4096];     // [g_t(8)][d(64)][8]
    __shared__ unsigned short ZTb[2][1024];     // [g_t(8)][lj(16)][8] own slice
    __shared__ unsigned short Sb[1024];         // [g_d(8)][lj(16)][8]
    const int lane = threadIdx.x;
    const int l16 = lane & 15, quad = lane >> 4;

    f32x4 Sacc[4];   // (j = jb + quad*4 + r, d = dt*16 + l16)
#pragma unroll
    for (int dt = 0; dt < 4; dt++) Sacc[dt] = (f32x4)0.f;

    // prologue: stage chunk 0
    {
        const size_t cb0 = ((size_t)bh * 32) * 4096;
#pragma unroll
        for (int p = 0; p < 8; p++) async_cp16(Wg + cb0 + p * 512 + lane * 8, &Wb[0][p * 512]);
#pragma unroll
        for (int p = 0; p < 8; p++) async_cp16(KTg + cb0 + p * 512 + lane * 8, &KTb[0][p * 512]);
#pragma unroll
        for (int c = 0; c < 2; c++)
            async_cp16(ZTg + cb0 + (size_t)((c * 4 + (lane >> 4)) * 64 + jb + (lane & 15)) * 8,
                       &ZTb[0][c * 512]);
    }
    WAITV(0);

    for (int ch = 0; ch < 32; ch++) {
        const int cur = ch & 1, nxt = cur ^ 1;
        const size_t cbase = ((size_t)bh * 32 + ch) * 4096;

        // prefetch next chunk (drains under this chunk's compute)
        if (ch + 1 < 32) {
            const size_t cbn = cbase + 4096;
#pragma unroll
            for (int p = 0; p < 8; p++) async_cp16(Wg + cbn + p * 512 + lane * 8, &Wb[nxt][p * 512]);
#pragma unroll
            for (int p = 0; p < 8; p++) async_cp16(KTg + cbn + p * 512 + lane * 8, &KTb[nxt][p * 512]);
#pragma unroll
            for (int c = 0; c < 2; c++)
                async_cp16(ZTg + cbn + (size_t)((c * 4 + (lane >> 4)) * 64 + jb + (lane & 15)) * 8,
                           &ZTb[nxt][c * 512]);
        }

        // chunk-start S -> Sb (tiled, local j)
#pragma unroll
        for (int dt = 0; dt < 4; dt++) {
#pragma unroll
            for (int r = 0; r < 4; r++) {
                const int lj = quad * 4 + r;
                Sb[((2 * dt + (l16 >> 3)) * 16 + lj) * 8 + (l16 & 7)] = f2b(Sacc[dt][r]);
            }
        }
        // bulk copy Sb -> global Sg (own j-slice of the tiled layout)
        {
            const int gd = lane >> 3, lj0 = (lane & 7) * 2;
            uint4 s0 = *(const uint4*)&Sb[lane * 16];
            uint4 s1 = *(const uint4*)&Sb[lane * 16 + 8];
            *(uint4*)(Sg + cbase + (size_t)(gd * 64 + jb + lj0) * 8) = s0;
            *(uint4*)(Sg + cbase + (size_t)(gd * 64 + jb + lj0 + 1) * 8) = s1;
        }

        // MFMA1': T1^T[j][t] = sum_d Sb[j][d] * Wb[t][d]
        f32x4 t1[4];
#pragma unroll
        for (int tt = 0; tt < 4; tt++) t1[tt] = (f32x4)0.f;
#pragma unroll
        for (int kh = 0; kh < 2; kh++) {
            const int g = kh * 4 + quad;
            bf16x8 afr = *(const bf16x8*)&Sb[(g * 16 + l16) * 8];
#pragma unroll
            for (int tt = 0; tt < 4; tt++) {
                bf16x8 bfr = *(const bf16x8*)&Wb[cur][(g * 64 + tt * 16 + l16) * 8];
                t1[tt] = __builtin_amdgcn_mfma_f32_16x16x32_bf16(afr, bfr, t1[tt], 0, 0, 0);
            }
        }
        // Y = Z - T1: in-place into ZTb (as YT[lj][t])
#pragma unroll
        for (int tt = 0; tt < 4; tt++) {
            const int t = tt * 16 + l16;
            unsigned short ybf[4];
#pragma unroll
            for (int r = 0; r < 4; r++) {
                const int lj = quad * 4 + r;
                const float z = b2f(ZTb[cur][((t >> 3) * 16 + lj) * 8 + (t & 7)]);
                ybf[r] = f2b(z - t1[tt][r]);
            }
#pragma unroll
            for (int r = 0; r < 4; r++) {
                const int lj = quad * 4 + r;
                ZTb[cur][((t >> 3) * 16 + lj) * 8 + (t & 7)] = ybf[r];
            }
        }
        // MFMA2: S[j][d] += sum_t YT[j][t] * KT[d][t]
#pragma unroll
        for (int kh = 0; kh < 2; kh++) {
            const int g = kh * 4 + quad;
            bf16x8 afr = *(const bf16x8*)&ZTb[cur][(g * 16 + l16) * 8];
#pragma unroll
            for (int dt = 0; dt < 4; dt++) {
                bf16x8 bfr = *(const bf16x8*)&KTb[cur][(g * 64 + dt * 16 + l16) * 8];
                Sacc[dt] = __builtin_amdgcn_mfma_f32_16x16x32_bf16(afr, bfr, Sacc[dt], 0, 0, 0);
            }
        }
        // bulk copy YT (own j-slice) -> global YTg
        {
            const int gt = lane >> 3, lj0 = (lane & 7) * 2;
            uint4 y0 = *(const uint4*)&ZTb[cur][lane * 16];
            uint4 y1 = *(const uint4*)&ZTb[cur][lane * 16 + 8];
            *(uint4*)(YTg + cbase + (size_t)(gt * 64 + jb + lj0) * 8) = y0;
            *(uint4*)(YTg + cbase + (size_t)(gt * 64 + jb + lj0 + 1) * 8) = y1;
        }
        WAITV(0);    // next chunk's tiles landed
    }
}

// ---------- output (MFMA): per (bh, chunk): O = Q S_c^T + tril(Q Kn^T) Y ----------
__global__ __launch_bounds__(256) void gdn_out(
    const unsigned short* __restrict__ qkv, const unsigned short* __restrict__ YTg,
    const unsigned short* __restrict__ Sg, unsigned short* __restrict__ attn)
{
    const int chunk = blockIdx.x, bh = blockIdx.y;
    const int b = bh >> 4, h = bh & 15;
    __shared__ unsigned short QbU[8 * 516];   // [g_d][t][8]  Q
    __shared__ unsigned short KbU[8 * 516];   // [g_d][s][8]  Kn
    __shared__ unsigned short StU[8 * 516];   // [g_d][j][8]  S
    __shared__ unsigned short YtU[8 * 516];   // [g_s][j][8]  Y^T
    __shared__ unsigned short MhU[8 * 516];   // [g_s][t][8]  M hi
    __shared__ unsigned short MlU[8 * 516];   // [g_s][t][8]  M lo
    const int tid = threadIdx.x;
    const int wid = tid >> 6, lane = tid & 63;
    const int l16 = lane & 15, quad = lane >> 4;
    const size_t cbase = ((size_t)bh * 32 + chunk) * 4096;

    // ---- stage: Q,K from qkv rows; St,Yt from packed tiled global ----
    {
        const int t = tid >> 2, c = tid & 3;
        const unsigned short* rowp = qkv + (size_t)(b * 2048 + chunk * 64 + t) * 3200;
        uint4 qa = *(const uint4*)(rowp + h * 64 + 16 * c);
        uint4 qb = *(const uint4*)(rowp + h * 64 + 16 * c + 8);
        uint4 ka = *(const uint4*)(rowp + 1024 + h * 64 + 16 * c);
        uint4 kb = *(const uint4*)(rowp + 1024 + h * 64 + 16 * c + 8);
        *(uint4*)&QbU[(2 * c) * 516 + t * 8]     = qa;
        *(uint4*)&QbU[(2 * c + 1) * 516 + t * 8] = qb;
        *(uint4*)&KbU[(2 * c) * 516 + t * 8]     = ka;
        *(uint4*)&KbU[(2 * c + 1) * 516 + t * 8] = kb;
        const int g = tid >> 5, row = (tid * 2) & 63;
        uint4 s0 = *(const uint4*)(Sg + cbase + tid * 16);
        uint4 s1 = *(const uint4*)(Sg + cbase + tid * 16 + 8);
        *(uint4*)&StU[g * 516 + row * 8]       = s0;
        *(uint4*)&StU[g * 516 + (row + 1) * 8] = s1;
        uint4 y0 = *(const uint4*)(YTg + cbase + tid * 16);
        uint4 y1 = *(const uint4*)(YTg + cbase + tid * 16 + 8);
        *(uint4*)&YtU[g * 516 + row * 8]       = y0;
        *(uint4*)&YtU[g * 516 + (row + 1) * 8] = y1;
    }
    __syncthreads();

    f32x4 m[4], o[4];
#pragma unroll
    for (int i = 0; i < 4; i++) { m[i] = (f32x4)0.f; o[i] = (f32x4)0.f; }

    // M = Q Kn^T  and  O1 = Q S^T   (A = Q rows of own t-block)
#pragma unroll
    for (int kh = 0; kh < 2; kh++) {
        const int g = kh * 4 + quad;
        bf16x8 afr = *(const bf16x8*)&QbU[g * 516 + (wid * 16 + l16) * 8];
#pragma unroll
        for (int st = 0; st < 4; st++) {
            bf16x8 bk = *(const bf16x8*)&KbU[g * 516 + (st * 16 + l16) * 8];
            m[st] = __builtin_amdgcn_mfma_f32_16x16x32_bf16(afr, bk, m[st], 0, 0, 0);
        }
#pragma unroll
        for (int jt = 0; jt < 4; jt++) {
            bf16x8 bs_ = *(const bf16x8*)&StU[g * 516 + (jt * 16 + l16) * 8];
            o[jt] = __builtin_amdgcn_mfma_f32_16x16x32_bf16(afr, bs_, o[jt], 0, 0, 0);
        }
    }

    // tril mask + bf16 hi/lo split -> MbU tiled [g_s][t][8]
#pragma unroll
    for (int st = 0; st < 4; st++) {
#pragma unroll
        for (int r = 0; r < 4; r++) {
            const int t = wid * 16 + quad * 4 + r;
            const int s = st * 16 + l16;
            float v = (s <= t) ? m[st][r] : 0.f;
            unsigned short hi = f2b(v);
            unsigned short lo = f2b(v - b2f(hi));
            const int addr = (s >> 3) * 516 + t * 8 + (s & 7);
            MhU[addr] = hi;
            MlU[addr] = lo;
        }
    }
    __syncthreads();

    // O += (Mhi + Mlo) * Y
#pragma unroll
    for (int kh = 0; kh < 2; kh++) {
        const int g = kh * 4 + quad;
        bf16x8 ah = *(const bf16x8*)&MhU[g * 516 + (wid * 16 + l16) * 8];
        bf16x8 al = *(const bf16x8*)&MlU[g * 516 + (wid * 16 + l16) * 8];
#pragma unroll
        for (int jt = 0; jt < 4; jt++) {
            bf16x8 by = *(const bf16x8*)&YtU[g * 516 + (jt * 16 + l16) * 8];
            o[jt] = __builtin_amdgcn_mfma_f32_16x16x32_bf16(ah, by, o[jt], 0, 0, 0);
            o[jt] = __builtin_amdgcn_mfma_f32_16x16x32_bf16(al, by, o[jt], 0, 0, 0);
        }
    }

    // epilogue: attn[t][h*64 + j] bf16
#pragma unroll
    for (int jt = 0; jt < 4; jt++) {
#pragma unroll
        for (int r = 0; r < 4; r++) {
            const int t = wid * 16 + quad * 4 + r;
            attn[(size_t)(b * 2048 + chunk * 64 + t) * 1024 + h * 64 + jt * 16 + l16] = f2b(o[jt][r]);
        }
    }
}

// ---------- workspace layout (bytes) ----------
static constexpr size_t OFF_H     = 0;                          // 16,777,216  hbuf bf16 / Sg bf16
static constexpr size_t OFF_WQKVT = OFF_H + 16777216;           //  6,553,600  (unused this rev)
static constexpr size_t OFF_WOT   = OFF_WQKVT + 6553600;        //  2,097,152
static constexpr size_t OFF_W1T   = OFF_WOT + 2097152;          //  8,388,608
static constexpr size_t OFF_W2T   = OFF_W1T + 8388608;          //  8,388,608
static constexpr size_t OFF_BIAS  = OFF_W2T + 8388608;          //     16,384
static constexpr size_t OFF_QKV   = OFF_BIAS + 16384;           // 67,108,864  qkv bf16 / gbuf bf16
static constexpr size_t OFF_ATTN  = OFF_QKV + 67108864;         // 16,777,216  bf16
static constexpr size_t OFF_Y1    = OFF_ATTN + 16777216;        // 33,554,432  y1 f32 / (ZTg+KTg bf16)
static constexpr size_t OFF_WG    = OFF_Y1 + 33554432;          // 16,777,216  Wg bf16 / wqkvT(3328x1024) early
static constexpr size_t OFF_YG    = OFF_WG + 16777216;          // 16,777,216  YTg bf16

extern "C" void kernel_launch(void* const* d_in, const int* in_sizes, int n_in,
                              void* d_out, int out_size, void* d_ws, size_t ws_size,
                              hipStream_t stream)
{
    const float* x     = (const float*)d_in[0];
    const float* wq    = (const float*)d_in[1];
    const float* bq    = (const float*)d_in[2];
    const float* wk    = (const float*)d_in[3];
    const float* bk    = (const float*)d_in[4];
    const float* wv    = (const float*)d_in[5];
    const float* bv    = (const float*)d_in[6];
    const float* wbeta = (const float*)d_in[7];
    const float* bbeta = (const float*)d_in[8];
    const float* wo    = (const float*)d_in[9];
    const float* bo    = (const float*)d_in[10];
    const float* w1    = (const float*)d_in[11];
    const float* b1    = (const float*)d_in[12];
    const float* w2    = (const float*)d_in[13];
    const float* b2    = (const float*)d_in[14];
    const float* ln1   = (const float*)d_in[15];
    const float* ln2   = (const float*)d_in[16];

    char* ws = (char*)d_ws;
    unsigned short* hbuf  = (unsigned short*)(ws + OFF_H);
    unsigned short* Sg    = (unsigned short*)(ws + OFF_H);
    unsigned short* wqkvT = (unsigned short*)(ws + OFF_WG);
    unsigned short* woT   = (unsigned short*)(ws + OFF_WOT);
    unsigned short* w1T   = (unsigned short*)(ws + OFF_W1T);
    unsigned short* w2T   = (unsigned short*)(ws + OFF_W2T);
    float*          biasc = (float*)(ws + OFF_BIAS);
    unsigned short* qkvU  = (unsigned short*)(ws + OFF_QKV);
    unsigned short* gbuf  = (unsigned short*)(ws + OFF_QKV);
    unsigned short* attn  = (unsigned short*)(ws + OFF_ATTN);
    float*          y1    = (float*)(ws + OFF_Y1);
    unsigned short* ZTg   = (unsigned short*)(ws + OFF_Y1);
    unsigned short* KTg   = (unsigned short*)(ws + OFF_Y1 + 16777216);
    unsigned short* Wg    = (unsigned short*)(ws + OFF_WG);
    unsigned short* YTg   = (unsigned short*)(ws + OFF_YG);
    float*          out   = (float*)d_out;

    // all weight transposes + bias concat in one launch (saves 7 launch gaps)
    weight_prep_k<<<12557, 256, 0, stream>>>(wq, wk, wv, wbeta, wo, w1, w2,
                                             wqkvT, woT, w1T, w2T,
                                             bq, bk, bv, bbeta, biasc);

    // layer
    rmsnorm_cast_k<<<8192, 256, 0, stream>>>(x, ln1, hbuf);
    // QKV: N padded to 3328 (13 col-tiles), stores guarded at 3200
    gemm256<false, true><<<dim3(32, 13), 512, 0, stream>>>(hbuf, wqkvT, biasc, qkvU, 3200, 3200, 1024);
    gdn_prep<<<dim3(32, 64), 256, 0, stream>>>(qkvU, Wg, ZTg, KTg);
    // prop: j-split x4, 1 wave per block, bh-major grid for XCD-shared W/KT
    gdn_prop_mfma<<<dim3(64, 4), 64, 0, stream>>>(Wg, KTg, ZTg, Sg, YTg);
    gdn_out<<<dim3(32, 64), 256, 0, stream>>>(qkvU, YTg, Sg, attn);
    // WO: 128x256 tiles -> grid 64x4 = 256 blocks (full GPU)
    gemm128n256<true><<<dim3(64, 4), 512, 0, stream>>>(attn, woT, bo, x, y1, 1024, 1024);
    rmsnorm_cast_k<<<8192, 256, 0, stream>>>(y1, ln2, hbuf);
    // FFN1: gelu + bf16
    gemm256<true, false><<<dim3(32, 16), 512, 0, stream>>>(hbuf, w1T, b1, gbuf, 4096, 4096, 1024);
    // FFN2: K=4096, 128x256 tiles -> 256 blocks
    gemm128n256<true><<<dim3(64, 4), 512, 0, stream>>>(gbuf, w2T, b2, y1, out, 1024, 4096);
}

// Round 8
// 552.247 us; speedup vs baseline: 1.1722x; 1.0434x over previous
//
#include <hip/hip_runtime.h>

#define DEV __device__ __forceinline__

typedef short bf16x8 __attribute__((ext_vector_type(8)));
typedef float f32x4 __attribute__((ext_vector_type(4)));
typedef unsigned int uint;

// raw barrier / counted waits (no compiler-attached drains)
#define SBAR()   asm volatile("s_barrier" ::: "memory")
#define WAITV(n) asm volatile("s_waitcnt vmcnt(" #n ")" ::: "memory")
#define WAITL()  asm volatile("s_waitcnt lgkmcnt(0)" ::: "memory")

// ---------- helpers ----------
DEV unsigned short f2b(float f) {               // fp32 -> bf16 RNE
    uint u = __float_as_uint(f);
    u += 0x7fffu + ((u >> 16) & 1u);
    return (unsigned short)(u >> 16);
}
DEV uint packbf2(float a, float b) { return (uint)f2b(a) | ((uint)f2b(b) << 16); }
DEV float b2f(unsigned short s) { return __uint_as_float(((uint)s) << 16); }
DEV float b2f_lo(uint u) { return __uint_as_float(u << 16); }
DEV float b2f_hi(uint u) { return __uint_as_float(u & 0xffff0000u); }

DEV void async_cp16(const void* g, void* l) {   // global -> LDS, 16B/lane
    __builtin_amdgcn_global_load_lds(
        (const __attribute__((address_space(1))) unsigned int*)g,
        (__attribute__((address_space(3))) unsigned int*)l, 16, 0, 0);
}

DEV float quad_sum(float x) {                   // sum over 4-lane quad via DPP
    x += __int_as_float(__builtin_amdgcn_update_dpp(0, __float_as_int(x), 0xB1, 0xF, 0xF, true));
    x += __int_as_float(__builtin_amdgcn_update_dpp(0, __float_as_int(x), 0x4E, 0xF, 0xF, true));
    return x;
}

DEV float gelu_f(float u) {                     // tanh-approx gelu via sigmoid/exp
    float p = u + 0.044715f * u * u * u;
    float e = __expf(-1.5957691216f * p);       // 0.5(1+tanh(cp)) = sigmoid(2cp)
    return __fdividef(u, 1.f + e);
}

// decode 8 bf16 (uint4) -> 8 floats
DEV void dec8(uint4 p, float* o) {
    o[0] = b2f_lo(p.x); o[1] = b2f_hi(p.x); o[2] = b2f_lo(p.y); o[3] = b2f_hi(p.y);
    o[4] = b2f_lo(p.z); o[5] = b2f_hi(p.z); o[6] = b2f_lo(p.w); o[7] = b2f_hi(p.w);
}

// ---------- batched weight prep: all 7 transposes + bias concat in ONE launch ----------
__global__ __launch_bounds__(256) void weight_prep_k(
    const float* __restrict__ wq, const float* __restrict__ wk,
    const float* __restrict__ wv, const float* __restrict__ wbeta,
    const float* __restrict__ wo, const float* __restrict__ w1,
    const float* __restrict__ w2,
    unsigned short* __restrict__ wqkvT, unsigned short* __restrict__ woT,
    unsigned short* __restrict__ w1T, unsigned short* __restrict__ w2T,
    const float* __restrict__ bq, const float* __restrict__ bk,
    const float* __restrict__ bv, const float* __restrict__ bb,
    float* __restrict__ biasc)
{
    const int id = blockIdx.x;
    if (id >= 12544) {   // bias concat [bq|bk|bv|bbeta|0pad] -> 3328
        int i = (id - 12544) * 256 + threadIdx.x;
        if (i >= 3328) return;
        float v = 0.f;
        if (i < 1024)      v = bq[i];
        else if (i < 2048) v = bk[i - 1024];
        else if (i < 3072) v = bv[i - 2048];
        else if (i < 3088) v = bb[i - 3072];
        biasc[i] = v;
        return;
    }
    const float* in; unsigned short* out; int K, N, KT, loc;
    if (id < 1024)      { in = wq;    out = wqkvT;               K = 1024; N = 1024; KT = 32;  loc = id; }
    else if (id < 2048) { in = wk;    out = wqkvT + 1024 * 1024; K = 1024; N = 1024; KT = 32;  loc = id - 1024; }
    else if (id < 3072) { in = wv;    out = wqkvT + 2048 * 1024; K = 1024; N = 1024; KT = 32;  loc = id - 2048; }
    else if (id < 3328) { in = wbeta; out = wqkvT + 3072 * 1024; K = 1024; N = 16;   KT = 32;  loc = id - 3072; }
    else if (id < 4352) { in = wo;    out = woT;                 K = 1024; N = 1024; KT = 32;  loc = id - 3328; }
    else if (id < 8448) { in = w1;    out = w1T;                 K = 1024; N = 4096; KT = 32;  loc = id - 4352; }
    else                { in = w2;    out = w2T;                 K = 4096; N = 1024; KT = 128; loc = id - 8448; }
    const int k0 = (loc % KT) * 32, n0 = (loc / KT) * 32;

    __shared__ float tile[32][33];
    const int tx = threadIdx.x & 31, ty = threadIdx.x >> 5;   // ty 0..7
#pragma unroll
    for (int i = 0; i < 32; i += 8) {
        int n = n0 + tx;
        tile[ty + i][tx] = (n < N) ? in[(size_t)(k0 + ty + i) * N + n] : 0.0f;
    }
    __syncthreads();
#pragma unroll
    for (int i = 0; i < 32; i += 8) {
        out[(size_t)(n0 + ty + i) * K + (k0 + tx)] = f2b(tile[tx][ty + i]);
    }
}

// ---------- rmsnorm (rows of 1024) + cast to bf16 ----------
__global__ __launch_bounds__(256) void rmsnorm_cast_k(
    const float* __restrict__ x, const float* __restrict__ scale,
    unsigned short* __restrict__ out)
{
    const int row = blockIdx.x;
    const int t = threadIdx.x;
    const float4 v = *(const float4*)(x + (size_t)row * 1024 + t * 4);
    float ss = v.x * v.x + v.y * v.y + v.z * v.z + v.w * v.w;
#pragma unroll
    for (int off = 1; off < 64; off <<= 1) ss += __shfl_xor(ss, off);
    __shared__ float wsum[4];
    if ((t & 63) == 0) wsum[t >> 6] = ss;
    __syncthreads();
    const float tot = wsum[0] + wsum[1] + wsum[2] + wsum[3];
    const float inv = rsqrtf(tot * (1.0f / 1024.0f) + 1e-6f);
    const float4 sc = *(const float4*)(scale + t * 4);
    uint lo = (uint)f2b(v.x * inv * sc.x) | ((uint)f2b(v.y * inv * sc.y) << 16);
    uint hi = (uint)f2b(v.z * inv * sc.z) | ((uint)f2b(v.w * inv * sc.w) << 16);
    uint2 pkd; pkd.x = lo; pkd.y = hi;
    *(uint2*)(out + (size_t)row * 1024 + t * 4) = pkd;
}

// =====================================================================
// gemm256 (r8: 8-phase-style BK=64 pipeline): C[M,N](bf16) = A*BT^T
// 256x256 tile, 512 thr (8 waves = 2M x 4N), wave out 128x64, acc[8][4].
// 2 buffers x BK=64 (128 KiB). Per tile: 4 phases x 16 MFMA; B frags read
// once (ph1) and held in regs; A frags 4/phase. Stage 1 half-tile (128
// rows, 2 cp16/thread) per phase: ph1->A0(t+1), ph2->A1(t+1) [buf o],
// ph3->B0(t+2), ph4->B1(t+2) [buf c]. ONE counted wait per tile
// (WAITV(4) at ph1: confirms all 4 chunks of t, leaves B(t+1) in flight),
// 2 barriers per tile (ph1, ph3). Race-free: A of buf o last read at
// t-1.ph4 (< t.ph1 SBAR); B of buf c read only at t.ph1 (< t.ph3 SBAR).
// Swizzle: phys chunk = logical ^ (row&7); source pre-swizzled.
// =====================================================================
#define STG(dst, srcp, half, kt)                                                       \
    do {                                                                               \
        async_cp16(srcp + (size_t)((half) * 128) * K + ((kt) << 6),                    \
                   dst + ((half) * 128) * 64 + lds);                                   \
        async_cp16(srcp + (size_t)((half) * 128 + 64) * K + ((kt) << 6),               \
                   dst + ((half) * 128 + 64) * 64 + lds);                              \
    } while (0)

#define LD_A(MI0)                                                                      \
    do {                                                                               \
        af[0] = *(const bf16x8*)&Ab[arow0 + (MI0) * 1024 + k0];                        \
        af[1] = *(const bf16x8*)&Ab[arow0 + (MI0) * 1024 + k1];                        \
        af[2] = *(const bf16x8*)&Ab[arow0 + ((MI0) + 1) * 1024 + k0];                  \
        af[3] = *(const bf16x8*)&Ab[arow0 + ((MI0) + 1) * 1024 + k1];                  \
    } while (0)

#define PH_MFMA(MI0)                                                                   \
    do {                                                                               \
        __builtin_amdgcn_s_setprio(1);                                                 \
        _Pragma("unroll")                                                              \
        for (int kh = 0; kh < 2; kh++)                                                 \
            _Pragma("unroll")                                                          \
            for (int m = 0; m < 2; m++)                                                \
                _Pragma("unroll")                                                      \
                for (int ni = 0; ni < 4; ni++)                                         \
                    acc[(MI0) + m][ni] = __builtin_amdgcn_mfma_f32_16x16x32_bf16(      \
                        af[m * 2 + kh], bf[ni * 2 + kh], acc[(MI0) + m][ni], 0, 0, 0); \
        __builtin_amdgcn_s_setprio(0);                                                 \
    } while (0)

template <bool GELU, bool GUARD>
__global__ __launch_bounds__(512, 2) void gemm256(
    const unsigned short* __restrict__ A, const unsigned short* __restrict__ BT,
    const float* __restrict__ bias, unsigned short* __restrict__ C,
    int Nstride, int Nreal, int K)
{
    __shared__ __align__(16) unsigned short As[2][256 * 64];   // 2 x 32 KB
    __shared__ __align__(16) unsigned short Bs[2][256 * 64];   // 2 x 32 KB
    const int tid = threadIdx.x;
    const int wid = tid >> 6;
    const int lane = tid & 63;
    const int l16 = lane & 15, quad = lane >> 4;
    const int wm = wid & 1, wn = wid >> 1;
    const int m0 = blockIdx.x << 8, n0 = blockIdx.y << 8;

    // staging: thread -> row (wid*8 + lane>>3 within a 64-row call), phys chunk lane&7;
    // global source chunk pre-swizzled: logical = (lane&7) ^ (row&7)
    const int srow = (wid << 3) + (lane >> 3);
    const int scol = ((lane & 7) ^ ((lane >> 3) & 7)) << 3;
    const unsigned short* Ag = A + (size_t)(m0 + srow) * K + scol;
    const unsigned short* Bg = BT + (size_t)(n0 + srow) * K + scol;
    const int lds = (wid << 3) * 64;            // this wave's 8-row block (ush)

    f32x4 acc[8][4];
#pragma unroll
    for (int i = 0; i < 8; i++)
#pragma unroll
        for (int j = 0; j < 4; j++) acc[i][j] = (f32x4)0.f;

    // fragment addresses: row stride 64 ush; phys chunk = (kh*4+quad) ^ (l16&7)
    const int arow0 = ((wm << 7) + l16) << 6;
    const int brow0 = ((wn << 6) + l16) << 6;
    const int k0 = (quad ^ (l16 & 7)) << 3;
    const int k1 = k0 ^ 32;

    const int nt = K >> 6;
    // prologue: issue 6 chunks in steady-state age order
    STG(Bs[0], Bg, 0, 0); STG(Bs[0], Bg, 1, 0);
    STG(As[0], Ag, 0, 0); STG(As[0], Ag, 1, 0);
    STG(Bs[1], Bg, 0, 1); STG(Bs[1], Bg, 1, 1);

    for (int t = 0; t < nt; ++t) {
        const unsigned short* Ab = As[t & 1];
        const unsigned short* Bb = Bs[t & 1];
        unsigned short* An = As[(t + 1) & 1];
        unsigned short* Bn = Bs[t & 1];         // t+2 has same parity as t
        const bool s1 = (t + 1) < nt, s2 = (t + 2) < nt;
        if (s2) { WAITV(4); } else { WAITV(0); }
        SBAR();
        bf16x8 af[4], bf[8];
        // ---- ph1: B all + A mi0,1 ----
#pragma unroll
        for (int ni = 0; ni < 4; ni++) {
            bf[ni * 2]     = *(const bf16x8*)&Bb[brow0 + ni * 1024 + k0];
            bf[ni * 2 + 1] = *(const bf16x8*)&Bb[brow0 + ni * 1024 + k1];
        }
        LD_A(0);
        if (s1) { STG(An, Ag, 0, t + 1); }
        PH_MFMA(0);
        // ---- ph2: A mi2,3 ----
        LD_A(2);
        if (s1) { STG(An, Ag, 1, t + 1); }
        PH_MFMA(2);
        // ---- ph3: A mi4,5 (barrier: all waves' ph1 B-reads done) ----
        SBAR();
        LD_A(4);
        if (s2) { STG(Bn, Bg, 0, t + 2); }
        PH_MFMA(4);
        // ---- ph4: A mi6,7 ----
        LD_A(6);
        if (s2) { STG(Bn, Bg, 1, t + 2); }
        PH_MFMA(6);
    }

    // epilogue: bias (+gelu) + bf16 stores (32B coalesced per 16-lane group)
    float bv[4];
    const int ccol = n0 + (wn << 6) + l16;
#pragma unroll
    for (int ni = 0; ni < 4; ni++) bv[ni] = bias[ccol + ni * 16];
#pragma unroll
    for (int mi = 0; mi < 8; mi++) {
        const int row = m0 + (wm << 7) + mi * 16 + (quad << 2);
#pragma unroll
        for (int r = 0; r < 4; r++) {
            unsigned short* Crow = C + (size_t)(row + r) * Nstride + ccol;
#pragma unroll
            for (int ni = 0; ni < 4; ni++) {
                float v = acc[mi][ni][r] + bv[ni];
                if (GELU) v = gelu_f(v);
                if (!GUARD || (ccol + ni * 16) < Nreal) Crow[ni * 16] = f2b(v);
            }
        }
    }
}

// =====================================================================
// gemm128n256 (r5-proven): C[M,N](f32) = A[M,K] * BT[N,K]^T + bias (+add)
// 128x256 tile, 512 thr (8 waves = 2M x 4N), wave out 64x64, acc[4][4].
// =====================================================================
template <bool ADD>
__global__ __launch_bounds__(512, 2) void gemm128n256(
    const unsigned short* __restrict__ A, const unsigned short* __restrict__ BT,
    const float* __restrict__ bias, const float* __restrict__ add,
    float* __restrict__ C, int N, int K)
{
    __shared__ __align__(16) unsigned short As2[4][128 * 32];   // 4 x 8 KB
    __shared__ __align__(16) unsigned short Bs2[4][256 * 32];   // 4 x 16 KB
    const int tid = threadIdx.x;
    const int wid = tid >> 6;
    const int lane = tid & 63;
    const int l16 = lane & 15, quad = lane >> 4;
    const int wm = wid & 1, wn = wid >> 1;
    const int m0 = blockIdx.x << 7, n0 = blockIdx.y << 8;

    const int arow = (wid << 4) + (lane >> 2);
    const int brow = (wid << 5) + (lane >> 2);
    const int scol = ((lane & 3) ^ ((lane >> 3) & 3)) << 3;
    const unsigned short* Ag = A + (size_t)(m0 + arow) * K + scol;
    const unsigned short* Bg = BT + (size_t)(n0 + brow) * K + scol;
    const size_t rstep16 = (size_t)16 * K;
    const int lda = wid << 9;
    const int ldb = wid << 10;

    f32x4 acc[4][4];
#pragma unroll
    for (int i = 0; i < 4; i++)
#pragma unroll
        for (int j = 0; j < 4; j++) acc[i][j] = (f32x4)0.f;

    const int ksw = (quad ^ ((l16 >> 1) & 3)) << 3;
    const int aoff = ((wm << 6) + l16) * 32 + ksw;
    const int boff = ((wn << 6) + l16) * 32 + ksw;

    const int nt = K >> 5;
    async_cp16(Ag, &As2[0][lda]);
    async_cp16(Bg, &Bs2[0][ldb]);
    async_cp16(Bg + rstep16, &Bs2[0][ldb + 512]);
    async_cp16(Ag + 32, &As2[1][lda]);
    async_cp16(Bg + 32, &Bs2[1][ldb]);
    async_cp16(Bg + 32 + rstep16, &Bs2[1][ldb + 512]);
    WAITV(3);
    SBAR();

    for (int tb = 0; tb < nt; tb += 4) {
#pragma unroll
        for (int u = 0; u < 4; ++u) {
            const int t = tb + u;
            const int pb = (u + 2) & 3;
            const bool st = (t + 2) < nt;
            const size_t kpre = (size_t)(t + 2) << 5;
            bf16x8 af[4], bfr[4];
#pragma unroll
            for (int mi = 0; mi < 4; mi++) af[mi] = *(const bf16x8*)&As2[u][aoff + mi * 512];
#pragma unroll
            for (int ni = 0; ni < 4; ni++) bfr[ni] = *(const bf16x8*)&Bs2[u][boff + ni * 512];
            if (st) {
                async_cp16(Ag + kpre, &As2[pb][lda]);
                async_cp16(Bg + kpre, &Bs2[pb][ldb]);
                async_cp16(Bg + kpre + rstep16, &Bs2[pb][ldb + 512]);
                WAITV(3);
            } else {
                WAITV(0);
            }
            SBAR();
            __builtin_amdgcn_s_setprio(1);
#pragma unroll
            for (int mi = 0; mi < 4; mi++)
#pragma unroll
                for (int ni = 0; ni < 4; ni++)
                    acc[mi][ni] = __builtin_amdgcn_mfma_f32_16x16x32_bf16(af[mi], bfr[ni], acc[mi][ni], 0, 0, 0);
            __builtin_amdgcn_s_setprio(0);
            SBAR();
        }
    }

    const int ccol = n0 + (wn << 6) + l16;
    float bv[4];
#pragma unroll
    for (int ni = 0; ni < 4; ni++) bv[ni] = bias[ccol + ni * 16];
#pragma unroll
    for (int mi = 0; mi < 4; mi++) {
        const int row = m0 + (wm << 6) + mi * 16 + (quad << 2);
#pragma unroll
        for (int r = 0; r < 4; r++) {
#pragma unroll
            for (int ni = 0; ni < 4; ni++) {
                size_t idx = (size_t)(row + r) * N + ccol + ni * 16;
                float v = acc[mi][ni][r] + bv[ni];
                if (ADD) v += add[idx];
                C[idx] = v;
            }
        }
    }
}

// =====================================================================
// Chunked WY delta-rule scan, chunk L=64 (all bf16 tensors, MFMA).
// Tiled global layouts per (bh,ch), flat 4096 ush = 8KB:
//   Wg  : [g_d(8)][t(64)][8]   W[t][d]
//   KTg : [g_t(8)][d(64)][8]   Kn[t][d] transposed
//   ZTg : [g_t(8)][j(64)][8]   Z[t][j] transposed
//   Sg  : [g_d(8)][j(64)][8]   chunk-start S[j][d] tiled
//   YTg : [g_t(8)][j(64)][8]   Y^T tiled
// =====================================================================

// ---------- prep: normalize k in place, build A (MFMA), solve W,Z, emit tiled layouts ----------
__global__ __launch_bounds__(256) void gdn_prep(
    unsigned short* __restrict__ qkv, unsigned short* __restrict__ Wg,
    unsigned short* __restrict__ ZTg, unsigned short* __restrict__ KTg)
{
    const int chunk = blockIdx.x, bh = blockIdx.y;
    const int b = bh >> 4, h = bh & 15;
    __shared__ float Ks[64 * 68];
    __shared__ float Ws[64 * 65];
    __shared__ float Zs[64 * 65];
    __shared__ float Asl[64 * 65];
    __shared__ float bs[64];
    __shared__ __align__(16) unsigned short KTb[4096];   // [g_d(8)][t(64)][8] bf16 Kn
    const int tid = threadIdx.x;
    const int t = tid >> 2, c = tid & 3;
    unsigned short* rowp = qkv + (size_t)(b * 2048 + chunk * 64 + t) * 3200;

    // phase 1a: load k slice (bf16), row norm, write Kn to LDS (f32 + bf16 tiled) + global
    float kn[16];
    {
        uint4 ka = *(const uint4*)(rowp + 1024 + h * 64 + 16 * c);
        uint4 kb = *(const uint4*)(rowp + 1024 + h * 64 + 16 * c + 8);
        dec8(ka, kn); dec8(kb, kn + 8);
    }
    float ss = 0.f;
#pragma unroll
    for (int j = 0; j < 16; j++) ss += kn[j] * kn[j];
    ss = quad_sum(ss);
    const float inv = 1.f / (sqrtf(ss) + 1e-6f);
#pragma unroll
    for (int j = 0; j < 16; j++) kn[j] *= inv;
#pragma unroll
    for (int j = 0; j < 16; j++) Ks[t * 68 + 16 * c + j] = kn[j];
    {
        uint4 p0, p1;
        p0.x = packbf2(kn[0], kn[1]);  p0.y = packbf2(kn[2], kn[3]);
        p0.z = packbf2(kn[4], kn[5]);  p0.w = packbf2(kn[6], kn[7]);
        p1.x = packbf2(kn[8], kn[9]);  p1.y = packbf2(kn[10], kn[11]);
        p1.z = packbf2(kn[12], kn[13]); p1.w = packbf2(kn[14], kn[15]);
        *(uint4*)(rowp + 1024 + h * 64 + 16 * c) = p0;
        *(uint4*)(rowp + 1024 + h * 64 + 16 * c + 8) = p1;
        *(uint4*)&KTb[((2 * c) * 64 + t) * 8]     = p0;   // d-group 2c
        *(uint4*)&KTb[((2 * c + 1) * 64 + t) * 8] = p1;   // d-group 2c+1
    }
    if (c == 0) bs[t] = 1.f / (1.f + __expf(-b2f(rowp[3072 + h])));
    __syncthreads();

    // phase 1b: RHS: W = beta*Kn, Z = beta*V
    const float beta = bs[t];
#pragma unroll
    for (int j = 0; j < 16; j++) Ws[t * 65 + 16 * c + j] = beta * kn[j];
    {
        float vv[16];
        uint4 va = *(const uint4*)(rowp + 2048 + h * 64 + 16 * c);
        uint4 vb = *(const uint4*)(rowp + 2048 + h * 64 + 16 * c + 8);
        dec8(va, vv); dec8(vb, vv + 8);
#pragma unroll
        for (int j = 0; j < 16; j++) Zs[t * 65 + 16 * c + j] = beta * vv[j];
    }
    __syncthreads();

    // phase 2 (MFMA): A = strictly_lower(diag(beta) Kn Kn^T)
    // wave w owns t-rows 16w..16w+15; same verified pattern as gdn_out's M.
    {
        const int wid2 = tid >> 6, lane2 = tid & 63;
        const int l16 = lane2 & 15, quad = lane2 >> 4;
        f32x4 am[4];
#pragma unroll
        for (int st = 0; st < 4; st++) am[st] = (f32x4)0.f;
#pragma unroll
        for (int kh = 0; kh < 2; kh++) {
            const int g = kh * 4 + quad;
            bf16x8 afr = *(const bf16x8*)&KTb[(g * 64 + wid2 * 16 + l16) * 8];
#pragma unroll
            for (int st = 0; st < 4; st++) {
                bf16x8 bfr = *(const bf16x8*)&KTb[(g * 64 + st * 16 + l16) * 8];
                am[st] = __builtin_amdgcn_mfma_f32_16x16x32_bf16(afr, bfr, am[st], 0, 0, 0);
            }
        }
#pragma unroll
        for (int st = 0; st < 4; st++)
#pragma unroll
            for (int r = 0; r < 4; r++) {
                const int T = wid2 * 16 + quad * 4 + r;
                const int S_ = st * 16 + l16;
                Asl[T * 65 + S_] = (S_ < T) ? bs[T] * am[st][r] : 0.f;
            }
    }
    __syncthreads();

    // phase 3: blocked forward substitution (I+A)X = RHS for W and Z
    {
        const int wid = tid >> 6, lane = tid & 63;  // lane = d
        for (int qi = 0; qi < 4; qi++) {
            if (qi > 0) {
                const int tb = qi * 16 + wid * 4;
                float aw[4], az[4];
#pragma unroll
                for (int i = 0; i < 4; i++) { aw[i] = Ws[(tb + i) * 65 + lane]; az[i] = Zs[(tb + i) * 65 + lane]; }
                for (int s = 0; s < qi * 16; s++) {
                    float wsv = Ws[s * 65 + lane], zsv = Zs[s * 65 + lane];
#pragma unroll
                    for (int i = 0; i < 4; i++) {
                        float a = Asl[(tb + i) * 65 + s];
                        aw[i] -= a * wsv; az[i] -= a * zsv;
                    }
                }
#pragma unroll
                for (int i = 0; i < 4; i++) { Ws[(tb + i) * 65 + lane] = aw[i]; Zs[(tb + i) * 65 + lane] = az[i]; }
            }
            __syncthreads();
            if (wid == 0) {
                for (int T = qi * 16; T < qi * 16 + 16; T++) {
                    float a_ = Ws[T * 65 + lane];
                    for (int s = qi * 16; s < T; s++) a_ -= Asl[T * 65 + s] * Ws[s * 65 + lane];
                    Ws[T * 65 + lane] = a_;
                }
            } else if (wid == 1) {
                for (int T = qi * 16; T < qi * 16 + 16; T++) {
                    float a_ = Zs[T * 65 + lane];
                    for (int s = qi * 16; s < T; s++) a_ -= Asl[T * 65 + s] * Zs[s * 65 + lane];
                    Zs[T * 65 + lane] = a_;
                }
            }
            __syncthreads();
        }
    }

    // phase 4: tiled bf16 outputs
    const size_t cbase = ((size_t)bh * 32 + chunk) * 4096;
    // Wg [g_d][t][8] from Ws[t][d]
    {
#pragma unroll
        for (int half = 0; half < 2; half++) {
            uint4 w4;
            w4.x = packbf2(Ws[t * 65 + 16 * c + half * 8 + 0], Ws[t * 65 + 16 * c + half * 8 + 1]);
            w4.y = packbf2(Ws[t * 65 + 16 * c + half * 8 + 2], Ws[t * 65 + 16 * c + half * 8 + 3]);
            w4.z = packbf2(Ws[t * 65 + 16 * c + half * 8 + 4], Ws[t * 65 + 16 * c + half * 8 + 5]);
            w4.w = packbf2(Ws[t * 65 + 16 * c + half * 8 + 6], Ws[t * 65 + 16 * c + half * 8 + 7]);
            *(uint4*)(Wg + cbase + (size_t)((2 * c + half) * 64 + t) * 8) = w4;
        }
    }
    // ZTg [g_t][j][8] from Zs[t][j]
    {
        const int jj = tid >> 2, tq = tid & 3;
#pragma unroll
        for (int half = 0; half < 2; half++) {
            uint4 z4;
            int i0 = half * 8;
            z4.x = packbf2(Zs[(16 * tq + i0 + 0) * 65 + jj], Zs[(16 * tq + i0 + 1) * 65 + jj]);
            z4.y = packbf2(Zs[(16 * tq + i0 + 2) * 65 + jj], Zs[(16 * tq + i0 + 3) * 65 + jj]);
            z4.z = packbf2(Zs[(16 * tq + i0 + 4) * 65 + jj], Zs[(16 * tq + i0 + 5) * 65 + jj]);
            z4.w = packbf2(Zs[(16 * tq + i0 + 6) * 65 + jj], Zs[(16 * tq + i0 + 7) * 65 + jj]);
            *(uint4*)(ZTg + cbase + (size_t)((2 * tq + half) * 64 + jj) * 8) = z4;
        }
    }
    // KTg [g_t][d][8] from Ks[t][d]
    {
        const int dd = tid >> 2, tq = tid & 3;
#pragma unroll
        for (int half = 0; half < 2; half++) {
            uint4 k4;
            int i0 = half * 8;
            k4.x = packbf2(Ks[(16 * tq + i0 + 0) * 68 + dd], Ks[(16 * tq + i0 + 1) * 68 + dd]);
            k4.y = packbf2(Ks[(16 * tq + i0 + 2) * 68 + dd], Ks[(16 * tq + i0 + 3) * 68 + dd]);
            k4.z = packbf2(Ks[(16 * tq + i0 + 4) * 68 + dd], Ks[(16 * tq + i0 + 5) * 68 + dd]);
            k4.w = packbf2(Ks[(16 * tq + i0 + 6) * 68 + dd], Ks[(16 * tq + i0 + 7) * 68 + dd]);
            *(uint4*)(KTg + cbase + (size_t)((2 * tq + half) * 64 + dd) * 8) = k4;
        }
    }
}

// ---------- prop (MFMA, j-split x4): grid (64 bh, 4 js), ONE wave per block ----------
__global__ __launch_bounds__(64, 1) void gdn_prop_mfma(
    const unsigned short* __restrict__ Wg, const unsigned short* __restrict__ KTg,
    const unsigned short* __restrict__ ZTg, unsigned short* __restrict__ Sg,
    unsigned short* __restrict__ YTg)
{
    const int bh = blockIdx.x;
    const int jb = blockIdx.y << 4;             // own j-rows jb..jb+15
    __shared__ unsigned short Wb[2][4096];      // [g_d(8)][t(64)][8]
    __shared__ unsigned short KTb[2][4096];     // [g_t(8)][d(64)][8]
    __shared__ unsigned short ZTb[2][1024];     // [g_t(8)][lj(16)][8] own slice
    __shared__ unsigned short Sb[1024];         // [g_d(8)][lj(16)][8]
    const int lane = threadIdx.x;
    const int l16 = lane & 15, quad = lane >> 4;

    f32x4 Sacc[4];   // (j = jb + quad*4 + r, d = dt*16 + l16)
#pragma unroll
    for (int dt = 0; dt < 4; dt++) Sacc[dt] = (f32x4)0.f;

    // prologue: stage chunk 0
    {
        const size_t cb0 = ((size_t)bh * 32) * 4096;
#pragma unroll
        for (int p = 0; p < 8; p++) async_cp16(Wg + cb0 + p * 512 + lane * 8, &Wb[0][p * 512]);
#pragma unroll
        for (int p = 0; p < 8; p++) async_cp16(KTg + cb0 + p * 512 + lane * 8, &KTb[0][p * 512]);
#pragma unroll
        for (int c = 0; c < 2; c++)
            async_cp16(ZTg + cb0 + (size_t)((c * 4 + (lane >> 4)) * 64 + jb + (lane & 15)) * 8,
                       &ZTb[0][c * 512]);
    }
    WAITV(0);

    for (int ch = 0; ch < 32; ch++) {
        const int cur = ch & 1, nxt = cur ^ 1;
        const size_t cbase = ((size_t)bh * 32 + ch) * 4096;

        // prefetch next chunk (drains under this chunk's compute)
        if (ch + 1 < 32) {
            const size_t cbn = cbase + 4096;
#pragma unroll
            for (int p = 0; p < 8; p++) async_cp16(Wg + cbn + p * 512 + lane * 8, &Wb[nxt][p * 512]);
#pragma unroll
            for (int p = 0; p < 8; p++) async_cp16(KTg + cbn + p * 512 + lane * 8, &KTb[nxt][p * 512]);
#pragma unroll
            for (int c = 0; c < 2; c++)
                async_cp16(ZTg + cbn + (size_t)((c * 4 + (lane >> 4)) * 64 + jb + (lane & 15)) * 8,
                           &ZTb[nxt][c * 512]);
        }

        // chunk-start S -> Sb (tiled, local j)
#pragma unroll
        for (int dt = 0; dt < 4; dt++) {
#pragma unroll
            for (int r = 0; r < 4; r++) {
                const int lj = quad * 4 + r;
                Sb[((2 * dt + (l16 >> 3)) * 16 + lj) * 8 + (l16 & 7)] = f2b(Sacc[dt][r]);
            }
        }
        // bulk copy Sb -> global Sg (own j-slice of the tiled layout)
        {
            const int gd = lane >> 3, lj0 = (lane & 7) * 2;
            uint4 s0 = *(const uint4*)&Sb[lane * 16];
            uint4 s1 = *(const uint4*)&Sb[lane * 16 + 8];
            *(uint4*)(Sg + cbase + (size_t)(gd * 64 + jb + lj0) * 8) = s0;
            *(uint4*)(Sg + cbase + (size_t)(gd * 64 + jb + lj0 + 1) * 8) = s1;
        }

        // MFMA1': T1^T[j][t] = sum_d Sb[j][d] * Wb[t][d]
        f32x4 t1[4];
#pragma unroll
        for (int tt = 0; tt < 4; tt++) t1[tt] = (f32x4)0.f;
#pragma unroll
        for (int kh = 0; kh < 2; kh++) {
            const int g = kh * 4 + quad;
            bf16x8 afr = *(const bf16x8*)&Sb[(g * 16 + l16) * 8];
#pragma unroll
            for (int tt = 0; tt < 4; tt++) {
                bf16x8 bfr = *(const bf16x8*)&Wb[cur][(g * 64 + tt * 16 + l16) * 8];
                t1[tt] = __builtin_amdgcn_mfma_f32_16x16x32_bf16(afr, bfr, t1[tt], 0, 0, 0);
            }
        }
        // Y = Z - T1: in-place into ZTb (as YT[lj][t])
#pragma unroll
        for (int tt = 0; tt < 4; tt++) {
            const int t = tt * 16 + l16;
            unsigned short ybf[4];
#pragma unroll
            for (int r = 0; r < 4; r++) {
                const int lj = quad * 4 + r;
                const float z = b2f(ZTb[cur][((t >> 3) * 16 + lj) * 8 + (t & 7)]);
                ybf[r] = f2b(z - t1[tt][r]);
            }
#pragma unroll
            for (int r = 0; r < 4; r++) {
                const int lj = quad * 4 + r;
                ZTb[cur][((t >> 3) * 16 + lj) * 8 + (t & 7)] = ybf[r];
            }
        }
        // MFMA2: S[j][d] += sum_t YT[j][t] * KT[d][t]
#pragma unroll
        for (int kh = 0; kh < 2; kh++) {
            const int g = kh * 4 + quad;
            bf16x8 afr = *(const bf16x8*)&ZTb[cur][(g * 16 + l16) * 8];
#pragma unroll
            for (int dt = 0; dt < 4; dt++) {
                bf16x8 bfr = *(const bf16x8*)&KTb[cur][(g * 64 + dt * 16 + l16) * 8];
                Sacc[dt] = __builtin_amdgcn_mfma_f32_16x16x32_bf16(afr, bfr, Sacc[dt], 0, 0, 0);
            }
        }
        // bulk copy YT (own j-slice) -> global YTg
        {
            const int gt = lane >> 3, lj0 = (lane & 7) * 2;
            uint4 y0 = *(const uint4*)&ZTb[cur][lane * 16];
            uint4 y1 = *(const uint4*)&ZTb[cur][lane * 16 + 8];
            *(uint4*)(YTg + cbase + (size_t)(gt * 64 + jb + lj0) * 8) = y0;
            *(uint4*)(YTg + cbase + (size_t)(gt * 64 + jb + lj0 + 1) * 8) = y1;
        }
        WAITV(0);    // next chunk's tiles landed
    }
}

// ---------- output (MFMA): per (bh, chunk): O = Q S_c^T + tril(Q Kn^T) Y ----------
__global__ __launch_bounds__(256) void gdn_out(
    const unsigned short* __restrict__ qkv, const unsigned short* __restrict__ YTg,
    const unsigned short* __restrict__ Sg, unsigned short* __restrict__ attn)
{
    const int chunk = blockIdx.x, bh = blockIdx.y;
    const int b = bh >> 4, h = bh & 15;
    __shared__ unsigned short QbU[8 * 516];   // [g_d][t][8]  Q
    __shared__ unsigned short KbU[8 * 516];   // [g_d][s][8]  Kn
    __shared__ unsigned short StU[8 * 516];   // [g_d][j][8]  S
    __shared__ unsigned short YtU[8 * 516];   // [g_s][j][8]  Y^T
    __shared__ unsigned short MhU[8 * 516];   // [g_s][t][8]  M hi
    __shared__ unsigned short MlU[8 * 516];   // [g_s][t][8]  M lo
    const int tid = threadIdx.x;
    const int wid = tid >> 6, lane = tid & 63;
    const int l16 = lane & 15, quad = lane >> 4;
    const size_t cbase = ((size_t)bh * 32 + chunk) * 4096;

    // ---- stage: Q,K from qkv rows; St,Yt from packed tiled global ----
    {
        const int t = tid >> 2, c = tid & 3;
        const unsigned short* rowp = qkv + (size_t)(b * 2048 + chunk * 64 + t) * 3200;
        uint4 qa = *(const uint4*)(rowp + h * 64 + 16 * c);
        uint4 qb = *(const uint4*)(rowp + h * 64 + 16 * c + 8);
        uint4 ka = *(const uint4*)(rowp + 1024 + h * 64 + 16 * c);
        uint4 kb = *(const uint4*)(rowp + 1024 + h * 64 + 16 * c + 8);
        *(uint4*)&QbU[(2 * c) * 516 + t * 8]     = qa;
        *(uint4*)&QbU[(2 * c + 1) * 516 + t * 8] = qb;
        *(uint4*)&KbU[(2 * c) * 516 + t * 8]     = ka;
        *(uint4*)&KbU[(2 * c + 1) * 516 + t * 8] = kb;
        const int g = tid >> 5, row = (tid * 2) & 63;
        uint4 s0 = *(const uint4*)(Sg + cbase + tid * 16);
        uint4 s1 = *(const uint4*)(Sg + cbase + tid * 16 + 8);
        *(uint4*)&StU[g * 516 + row * 8]       = s0;
        *(uint4*)&StU[g * 516 + (row + 1) * 8] = s1;
        uint4 y0 = *(const uint4*)(YTg + cbase + tid * 16);
        uint4 y1 = *(const uint4*)(YTg + cbase + tid * 16 + 8);
        *(uint4*)&YtU[g * 516 + row * 8]       = y0;
        *(uint4*)&YtU[g * 516 + (row + 1) * 8] = y1;
    }
    __syncthreads();

    f32x4 m[4], o[4];
#pragma unroll
    for (int i = 0; i < 4; i++) { m[i] = (f32x4)0.f; o[i] = (f32x4)0.f; }

    // M = Q Kn^T  and  O1 = Q S^T   (A = Q rows of own t-block)
#pragma unroll
    for (int kh = 0; kh < 2; kh++) {
        const int g = kh * 4 + quad;
        bf16x8 afr = *(const bf16x8*)&QbU[g * 516 + (wid * 16 + l16) * 8];
#pragma unroll
        for (int st = 0; st < 4; st++) {
            bf16x8 bk = *(const bf16x8*)&KbU[g * 516 + (st * 16 + l16) * 8];
            m[st] = __builtin_amdgcn_mfma_f32_16x16x32_bf16(afr, bk, m[st], 0, 0, 0);
        }
#pragma unroll
        for (int jt = 0; jt < 4; jt++) {
            bf16x8 bs_ = *(const bf16x8*)&StU[g * 516 + (jt * 16 + l16) * 8];
            o[jt] = __builtin_amdgcn_mfma_f32_16x16x32_bf16(afr, bs_, o[jt], 0, 0, 0);
        }
    }

    // tril mask + bf16 hi/lo split -> MbU tiled [g_s][t][8]
#pragma unroll
    for (int st = 0; st < 4; st++) {
#pragma unroll
        for (int r = 0; r < 4; r++) {
            const int t = wid * 16 + quad * 4 + r;
            const int s = st * 16 + l16;
            float v = (s <= t) ? m[st][r] : 0.f;
            unsigned short hi = f2b(v);
            unsigned short lo = f2b(v - b2f(hi));
            const int addr = (s >> 3) * 516 + t * 8 + (s & 7);
            MhU[addr] = hi;
            MlU[addr] = lo;
        }
    }
    __syncthreads();

    // O += (Mhi + Mlo) * Y
#pragma unroll
    for (int kh = 0; kh < 2; kh++) {
        const int g = kh * 4 + quad;
        bf16x8 ah = *(const bf16x8*)&MhU[g * 516 + (wid * 16 + l16) * 8];
        bf16x8 al = *(const bf16x8*)&MlU[g * 516 + (wid * 16 + l16) * 8];
#pragma unroll
        for (int jt = 0; jt < 4; jt++) {
            bf16x8 by = *(const bf16x8*)&YtU[g * 516 + (jt * 16 + l16) * 8];
            o[jt] = __builtin_amdgcn_mfma_f32_16x16x32_bf16(ah, by, o[jt], 0, 0, 0);
            o[jt] = __builtin_amdgcn_mfma_f32_16x16x32_bf16(al, by, o[jt], 0, 0, 0);
        }
    }

    // epilogue: attn[t][h*64 + j] bf16
#pragma unroll
    for (int jt = 0; jt < 4; jt++) {
#pragma unroll
        for (int r = 0; r < 4; r++) {
            const int t = wid * 16 + quad * 4 + r;
            attn[(size_t)(b * 2048 + chunk * 64 + t) * 1024 + h * 64 + jt * 16 + l16] = f2b(o[jt][r]);
        }
    }
}

// ---------- workspace layout (bytes) ----------
static constexpr size_t OFF_H     = 0;                          // 16,777,216  hbuf bf16 / Sg bf16
static constexpr size_t OFF_WQKVT = OFF_H + 16777216;           //  6,553,600  (unused this rev)
static constexpr size_t OFF_WOT   = OFF_WQKVT + 6553600;        //  2,097,152
static constexpr size_t OFF_W1T   = OFF_WOT + 2097152;          //  8,388,608
static constexpr size_t OFF_W2T   = OFF_W1T + 8388608;          //  8,388,608
static constexpr size_t OFF_BIAS  = OFF_W2T + 8388608;          //     16,384
static constexpr size_t OFF_QKV   = OFF_BIAS + 16384;           // 67,108,864  qkv bf16 / gbuf bf16
static constexpr size_t OFF_ATTN  = OFF_QKV + 67108864;         // 16,777,216  bf16
static constexpr size_t OFF_Y1    = OFF_ATTN + 16777216;        // 33,554,432  y1 f32 / (ZTg+KTg bf16)
static constexpr size_t OFF_WG    = OFF_Y1 + 33554432;          // 16,777,216  Wg bf16 / wqkvT(3328x1024) early
static constexpr size_t OFF_YG    = OFF_WG + 16777216;          // 16,777,216  YTg bf16

extern "C" void kernel_launch(void* const* d_in, const int* in_sizes, int n_in,
                              void* d_out, int out_size, void* d_ws, size_t ws_size,
                              hipStream_t stream)
{
    const float* x     = (const float*)d_in[0];
    const float* wq    = (const float*)d_in[1];
    const float* bq    = (const float*)d_in[2];
    const float* wk    = (const float*)d_in[3];
    const float* bk    = (const float*)d_in[4];
    const float* wv    = (const float*)d_in[5];
    const float* bv    = (const float*)d_in[6];
    const float* wbeta = (const float*)d_in[7];
    const float* bbeta = (const float*)d_in[8];
    const float* wo    = (const float*)d_in[9];
    const float* bo    = (const float*)d_in[10];
    const float* w1    = (const float*)d_in[11];
    const float* b1    = (const float*)d_in[12];
    const float* w2    = (const float*)d_in[13];
    const float* b2    = (const float*)d_in[14];
    const float* ln1   = (const float*)d_in[15];
    const float* ln2   = (const float*)d_in[16];

    char* ws = (char*)d_ws;
    unsigned short* hbuf  = (unsigned short*)(ws + OFF_H);
    unsigned short* Sg    = (unsigned short*)(ws + OFF_H);
    unsigned short* wqkvT = (unsigned short*)(ws + OFF_WG);
    unsigned short* woT   = (unsigned short*)(ws + OFF_WOT);
    unsigned short* w1T   = (unsigned short*)(ws + OFF_W1T);
    unsigned short* w2T   = (unsigned short*)(ws + OFF_W2T);
    float*          biasc = (float*)(ws + OFF_BIAS);
    unsigned short* qkvU  = (unsigned short*)(ws + OFF_QKV);
    unsigned short* gbuf  = (unsigned short*)(ws + OFF_QKV);
    unsigned short* attn  = (unsigned short*)(ws + OFF_ATTN);
    float*          y1    = (float*)(ws + OFF_Y1);
    unsigned short* ZTg   = (unsigned short*)(ws + OFF_Y1);
    unsigned short* KTg   = (unsigned short*)(ws + OFF_Y1 + 16777216);
    unsigned short* Wg    = (unsigned short*)(ws + OFF_WG);
    unsigned short* YTg   = (unsigned short*)(ws + OFF_YG);
    float*          out   = (float*)d_out;

    // all weight transposes + bias concat in one launch
    weight_prep_k<<<12557, 256, 0, stream>>>(wq, wk, wv, wbeta, wo, w1, w2,
                                             wqkvT, woT, w1T, w2T,
                                             bq, bk, bv, bbeta, biasc);

    // layer
    rmsnorm_cast_k<<<8192, 256, 0, stream>>>(x, ln1, hbuf);
    // QKV: N padded to 3328 (13 col-tiles), stores guarded at 3200
    gemm256<false, true><<<dim3(32, 13), 512, 0, stream>>>(hbuf, wqkvT, biasc, qkvU, 3200, 3200, 1024);
    gdn_prep<<<dim3(32, 64), 256, 0, stream>>>(qkvU, Wg, ZTg, KTg);
    // prop: j-split x4, 1 wave per block, bh-major grid for XCD-shared W/KT
    gdn_prop_mfma<<<dim3(64, 4), 64, 0, stream>>>(Wg, KTg, ZTg, Sg, YTg);
    gdn_out<<<dim3(32, 64), 256, 0, stream>>>(qkvU, YTg, Sg, attn);
    // WO: 128x256 tiles -> grid 64x4 = 256 blocks (full GPU)
    gemm128n256<true><<<dim3(64, 4), 512, 0, stream>>>(attn, woT, bo, x, y1, 1024, 1024);
    rmsnorm_cast_k<<<8192, 256, 0, stream>>>(y1, ln2, hbuf);
    // FFN1: gelu + bf16
    gemm256<true, false><<<dim3(32, 16), 512, 0, stream>>>(hbuf, w1T, b1, gbuf, 4096, 4096, 1024);
    // FFN2: K=4096, 128x256 tiles -> 256 blocks
    gemm128n256<true><<<dim3(64, 4), 512, 0, stream>>>(gbuf, w2T, b2, y1, out, 1024, 4096);
}